// Round 1
// baseline (3867.135 us; speedup 1.0000x reference)
//
#include <hip/hip_runtime.h>
#include <hip/hip_bf16.h>
#include <math.h>

typedef __bf16 bf16_t;
typedef __bf16 bf16x4_t __attribute__((ext_vector_type(4)));
typedef __bf16 bf16x8_t __attribute__((ext_vector_type(8)));
typedef float  f32x4_t  __attribute__((ext_vector_type(4)));

#define N_TOK 4096
#define D_IN  4096
#define O_OUT 4096
#define NEXP  8
#define NHEAD 3
#define RANK  16
#define KC2   384      // E*H*R
#define PCOLS 256      // padded projection cols (152 used)
#define SCALING_F 2.0f

// ---------------- prep building blocks ----------------

// 64x64 transpose tile fp32 -> bf16, vectorized, <=2-way LDS aliasing (free).
__device__ __forceinline__ void transpose_tile(const float* __restrict__ src,
                                               bf16_t* __restrict__ dst,
                                               int Rr, int Cc, int r0, int c0,
                                               float (*tile)[65]) {
  int q  = threadIdx.x & 15;
  int r4 = threadIdx.x >> 4;
  #pragma unroll
  for (int g = 0; g < 4; ++g) {
    int r = r4 + g * 16;
    float4 v = *(const float4*)(src + (size_t)(r0 + r) * Cc + c0 + q * 4);
    tile[r][q * 4 + 0] = v.x; tile[r][q * 4 + 1] = v.y;
    tile[r][q * 4 + 2] = v.z; tile[r][q * 4 + 3] = v.w;
  }
  __syncthreads();
  #pragma unroll
  for (int g = 0; g < 4; ++g) {
    int c = r4 + g * 16;
    bf16x4_t o = { (bf16_t)tile[q * 4 + 0][c], (bf16_t)tile[q * 4 + 1][c],
                   (bf16_t)tile[q * 4 + 2][c], (bf16_t)tile[q * 4 + 3][c] };
    *(bf16x4_t*)(dst + (size_t)(c0 + c) * Rr + r0 + q * 4) = o;
  }
}

// ---------------- ONE prep kernel: all independent pre-GEMM work ----------------
__global__ __launch_bounds__(256) void prep_kernel(const float* __restrict__ x,
                                                   const float* __restrict__ base_W,
                                                   const float* __restrict__ rw,
                                                   const float* __restrict__ A,
                                                   const float* __restrict__ B,
                                                   const float* __restrict__ Rm,
                                                   bf16_t* __restrict__ xb,
                                                   bf16_t* __restrict__ WbT,
                                                   bf16_t* __restrict__ BbT,
                                                   bf16_t* __restrict__ PabT,
                                                   int* __restrict__ gidx,
                                                   float* __restrict__ gwv) {
  __shared__ float tile[64][65];
  int b = blockIdx.x;
  if (b < 4096) {
    transpose_tile(base_W, WbT, 4096, 4096, (b & 63) * 64, (b >> 6) * 64, tile);
  } else if (b < 5120) {
    int lane = threadIdx.x & 63;
    int wv = threadIdx.x >> 6;
    int n = (b - 4096) * 4 + wv;
    const float4* xv = (const float4*)(x + (size_t)n * D_IN);
    bf16x4_t* xo = (bf16x4_t*)(xb + (size_t)n * D_IN);
    float acc[NEXP] = {0, 0, 0, 0, 0, 0, 0, 0};
    for (int d = lane; d < D_IN / 4; d += 64) {
      float4 xx = xv[d];
      bf16x4_t ob = { (bf16_t)xx.x, (bf16_t)xx.y, (bf16_t)xx.z, (bf16_t)xx.w };
      xo[d] = ob;
      #pragma unroll
      for (int e = 0; e < NEXP; ++e) {
        float4 ww = ((const float4*)(rw + (size_t)e * D_IN))[d];
        acc[e] += xx.x * ww.x + xx.y * ww.y + xx.z * ww.z + xx.w * ww.w;
      }
    }
    #pragma unroll
    for (int e = 0; e < NEXP; ++e) {
      float v = acc[e];
      #pragma unroll
      for (int o = 32; o > 0; o >>= 1) v += __shfl_down(v, o);
      acc[e] = v;
    }
    if (lane == 0) {
      int i0 = 0; float l0 = acc[0];
      #pragma unroll
      for (int e = 1; e < NEXP; ++e) if (acc[e] > l0) { l0 = acc[e]; i0 = e; }
      int i1 = -1; float l1 = -3.4e38f;
      #pragma unroll
      for (int e = 0; e < NEXP; ++e) if (e != i0 && acc[e] > l1) { l1 = acc[e]; i1 = e; }
      float w0 = 1.f / (1.f + expf(l1 - l0));
      gidx[2 * n] = i0; gidx[2 * n + 1] = i1;
      gwv[2 * n] = w0;  gwv[2 * n + 1] = 1.f - w0;
    }
  } else if (b < 5504) {
    int t = b - 5120;
    transpose_tile(B, BbT, KC2, 4096, (t % 6) * 64, (t / 6) * 64, tile);
  } else {
    int c = b - 5504;  // 0..255: output row of PabT
    for (int d = threadIdx.x; d < D_IN; d += 256) {
      float v = 0.f;
      if (c < 128) {
        int e = c >> 4, r = c & 15;
        v = A[((size_t)e * D_IN + d) * RANK + r];
      } else if (c < 152) {
        int qq = c - 128; int e = qq / 3, h = qq - 3 * e;
        v = Rm[((size_t)e * D_IN + d) * NHEAD + h];
      }
      PabT[(size_t)c * D_IN + d] = (bf16_t)v;
    }
  }
}

// ---------------- gating: C2[n, e*48+h*16+r], summing 4 split-K partials ----------------
__global__ void gating_kernel(const float* __restrict__ projP, const int* __restrict__ gidx,
                              const float* __restrict__ gwv, bf16_t* __restrict__ C2b) {
  int n = blockIdx.x;
  int c = threadIdx.x;  // 0..383
  int e = c / 48;
  int h = (c % 48) / 16;
  int r = c & 15;
  int i0 = gidx[2 * n], i1 = gidx[2 * n + 1];
  float g = (e == i0) ? gwv[2 * n] : (e == i1) ? gwv[2 * n + 1] : 0.f;
  float val = 0.f;
  if (g != 0.f) {
    const float* p0 = projP + (size_t)n * PCOLS;
    const size_t S = (size_t)N_TOK * PCOLS;
    #define RD(cc) (p0[(cc)] + p0[(cc) + S] + p0[(cc) + 2 * S] + p0[(cc) + 3 * S])
    float h0 = RD(128 + e * 3 + 0);
    float h1 = RD(128 + e * 3 + 1);
    float h2 = RD(128 + e * 3 + 2);
    float av = RD(e * 16 + r);
    #undef RD
    float mx = fmaxf(h0, fmaxf(h1, h2));
    float e0 = expf(h0 - mx), e1 = expf(h1 - mx), e2 = expf(h2 - mx);
    float hw = (h == 0 ? e0 : h == 1 ? e1 : e2) / (e0 + e1 + e2);
    val = SCALING_F * g * hw * av;
  }
  C2b[(size_t)n * KC2 + c] = (bf16_t)val;
}

// ---------------- m97-style MFMA K-loop core (used by proj GEMM only) ----------------
__device__ __forceinline__ void run_kloop(f32x4_t (&acc)[4][4], bf16_t* sA, bf16_t* sB,
                                          const bf16_t* __restrict__ Ab, int lda,
                                          const bf16_t* __restrict__ Bb, int ldb, int K) {
  const int tid = threadIdx.x;
  const int lane = tid & 63;
  const int w = tid >> 6;
  const int wm = (w >> 1) * 64;
  const int wn = (w & 1) * 64;
  const int qd = lane >> 4;
  const int ln = lane & 15;
  const int sw = ln & 7;

  size_t offA[4], offB[4];
  int lo[4];
  #pragma unroll
  for (int t = 0; t < 4; ++t) {
    int c = tid + t * 256;
    int m = c >> 3, kc = (c & 7) ^ (m & 7);
    offA[t] = (size_t)m * lda + kc * 8;
    offB[t] = (size_t)m * ldb + kc * 8;
    lo[t] = c * 8;
  }
  int rowA[4], rowB[4];
  #pragma unroll
  for (int i = 0; i < 4; ++i) {
    rowA[i] = (wm + i * 16 + ln) * 64;
    rowB[i] = (wn + i * 16 + ln) * 64;
  }

  for (int k0 = 0; k0 < K; k0 += 64) {
    __syncthreads();
    #pragma unroll
    for (int t = 0; t < 4; ++t)
      __builtin_amdgcn_global_load_lds(
          (const __attribute__((address_space(1))) void*)(Ab + k0 + offA[t]),
          (__attribute__((address_space(3))) void*)(sA + lo[t]), 16, 0, 0);
    #pragma unroll
    for (int t = 0; t < 4; ++t)
      __builtin_amdgcn_global_load_lds(
          (const __attribute__((address_space(1))) void*)(Bb + k0 + offB[t]),
          (__attribute__((address_space(3))) void*)(sB + lo[t]), 16, 0, 0);
    __syncthreads();
    #pragma unroll
    for (int s = 0; s < 2; ++s) {
      bf16x8_t af[4], bfr[4];
      int kx = ((s * 4 + qd) ^ sw) * 8;
      #pragma unroll
      for (int i = 0; i < 4; ++i) af[i]  = *(const bf16x8_t*)(sA + rowA[i] + kx);
      #pragma unroll
      for (int i = 0; i < 4; ++i) bfr[i] = *(const bf16x8_t*)(sB + rowB[i] + kx);
      #pragma unroll
      for (int i = 0; i < 4; ++i)
        #pragma unroll
        for (int j = 0; j < 4; ++j)
          acc[i][j] = __builtin_amdgcn_mfma_f32_16x16x32_bf16(af[i], bfr[j], acc[i][j], 0, 0, 0);
    }
  }
}

// proj split-K GEMM: projP[kz][4096,256] = xb @ PabT^T partial (K slice 1024), plain stores.
__global__ __launch_bounds__(256) void gemm_proj_kernel(const bf16_t* __restrict__ xb,
                                                        const bf16_t* __restrict__ PabT,
                                                        float* __restrict__ projP) {
  __shared__ bf16_t sA[128 * 64];
  __shared__ bf16_t sB[128 * 64];
  int bm = blockIdx.x, bn = blockIdx.y, kz = blockIdx.z;
  f32x4_t acc[4][4] = {};
  run_kloop(acc, sA, sB,
            xb + (size_t)bm * 128 * D_IN + kz * 1024, D_IN,
            PabT + (size_t)bn * 128 * D_IN + kz * 1024, D_IN, 1024);
  const int lane = threadIdx.x & 63, w = threadIdx.x >> 6;
  const int wm = (w >> 1) * 64, wn = (w & 1) * 64, qd = lane >> 4, ln = lane & 15;
  float* Cb = projP + (size_t)kz * N_TOK * PCOLS + (size_t)bm * 128 * PCOLS + bn * 128;
  #pragma unroll
  for (int i = 0; i < 4; ++i)
    #pragma unroll
    for (int j = 0; j < 4; ++j) {
      int col = wn + j * 16 + ln;
      #pragma unroll
      for (int rg = 0; rg < 4; ++rg) {
        int row = wm + i * 16 + qd * 4 + rg;
        Cb[(size_t)row * PCOLS + col] = acc[i][j][rg];
      }
    }
}

// ---------------- fused big GEMM, 256x256 tile, BK=32, ring-4 counted-vmcnt pipeline ----
// out = xb@WbT^T (K=4096) + C2b@BbT^T (K=384), single epilogue write.
// 512 threads = 8 waves (2 M-groups x 4 N-groups); per-wave output 128x64.
// LDS: 4-slot ring x (A 16KB + B 16KB) = 128 KiB -> 1 block/CU, 2 waves/SIMD.
// Schedule per K-tile t (main loop):
//   issue A-stage of tile t+3 (2 glds)          // slot (t+3)&3 == (t-1)&3, free since BAR_B(t-1)
//   s_waitcnt vmcnt(10)                          // tile t landed; t+1,t+2,t+3A stay in flight
//   s_barrier (all waves' tile-t loads visible)
//   issue B-stage of tile t+3 (2 glds)
//   12x ds_read_b128 (XOR-swizzled, conflict-free) + setprio(1) 32x MFMA setprio(0)
//   s_barrier (reads of slot t&3 done -> re-stageable next iter)
// Swizzle: 16B-chunk c' = c ^ ((row>>1)&3), applied to the PER-LANE GLOBAL SOURCE on
// stage (linear LDS dest, rule 21) and to the ds_read address (same involution).
__global__ __launch_bounds__(512, 2) void gemm_fused256(const bf16_t* __restrict__ xb,
                                                        const bf16_t* __restrict__ WbT,
                                                        const bf16_t* __restrict__ C2b,
                                                        const bf16_t* __restrict__ BbT,
                                                        float* __restrict__ out) {
  __shared__ __align__(16) bf16_t sring[4][2][8192];  // [slot][A/B][256 rows x 32 k]
  const int tid = threadIdx.x;
  const int lane = tid & 63;
  const int w = tid >> 6;
  const int wm = w >> 2;          // 0..1
  const int wn = w & 3;           // 0..3
  const int qd = lane >> 4;       // k-chunk
  const int ln = lane & 15;       // row-in-frag
  const int swz8 = ((qd ^ ((ln >> 1) & 3)) << 3);  // swizzled k-chunk, elem units

  // XCD-aware bijective swizzle (256 blocks, 256 % 8 == 0)
  int b = blockIdx.x;
  int sw = (b & 7) * 32 + (b >> 3);
  int bm = sw >> 4, bn = sw & 15;

  f32x4_t acc[8][4] = {};

  auto stage_op = [&](const bf16_t* __restrict__ G, int ld, int k0, bf16_t* lbase) {
    #pragma unroll
    for (int r = 0; r < 2; ++r) {
      int s = r * 512 + tid;            // 16B slot: row = s>>2, chunk' = s&3
      int row = s >> 2;
      int c = (s & 3) ^ ((row >> 1) & 3);  // inverse-swizzled source chunk
      __builtin_amdgcn_global_load_lds(
          (const __attribute__((address_space(1))) void*)(G + (size_t)row * ld + k0 + c * 8),
          (__attribute__((address_space(3))) void*)(lbase + s * 8), 16, 0, 0);
    }
  };

  auto compute = [&](int slot) {
    const bf16_t* pA = &sring[slot][0][0];
    const bf16_t* pB = &sring[slot][1][0];
    bf16x8_t af[8], bv[4];
    #pragma unroll
    for (int nj = 0; nj < 4; ++nj)
      bv[nj] = *(const bf16x8_t*)(pB + (wn * 64 + nj * 16 + ln) * 32 + swz8);
    #pragma unroll
    for (int mi = 0; mi < 8; ++mi)
      af[mi] = *(const bf16x8_t*)(pA + (wm * 128 + mi * 16 + ln) * 32 + swz8);
    __builtin_amdgcn_s_setprio(1);
    #pragma unroll
    for (int mi = 0; mi < 8; ++mi)
      #pragma unroll
      for (int nj = 0; nj < 4; ++nj)
        acc[mi][nj] = __builtin_amdgcn_mfma_f32_16x16x32_bf16(af[mi], bv[nj], acc[mi][nj], 0, 0, 0);
    __builtin_amdgcn_s_setprio(0);
  };

  auto kloop = [&](const bf16_t* __restrict__ A, int lda,
                   const bf16_t* __restrict__ B, int ldb, int K) {
    const int T = K / 32;               // >= 4 for both call sites (128, 12)
    #pragma unroll
    for (int t = 0; t < 3; ++t) {       // prologue: tiles 0..2 -> slots 0..2 (12 glds/wave)
      stage_op(A, lda, t * 32, &sring[t][0][0]);
      stage_op(B, ldb, t * 32, &sring[t][1][0]);
    }
    for (int t = 0; t < T - 3; ++t) {
      const int k3 = (t + 3) * 32, s3 = (t + 3) & 3;
      stage_op(A, lda, k3, &sring[s3][0][0]);            // +2 -> 14 outstanding
      asm volatile("s_waitcnt vmcnt(10)" ::: "memory");  // tile t fully landed (per wave)
      __builtin_amdgcn_s_barrier();
      __builtin_amdgcn_sched_barrier(0);
      stage_op(B, ldb, k3, &sring[s3][1][0]);            // interleaves with compute
      compute(t & 3);
      __builtin_amdgcn_sched_barrier(0);
      __builtin_amdgcn_s_barrier();                      // slot t&3 reads done
      __builtin_amdgcn_sched_barrier(0);
    }
    for (int t = T - 3; t < T; ++t) {   // tail: drain 8 -> 4 -> 0
      const int rem = T - t;
      if (rem == 3)      asm volatile("s_waitcnt vmcnt(8)" ::: "memory");
      else if (rem == 2) asm volatile("s_waitcnt vmcnt(4)" ::: "memory");
      else               asm volatile("s_waitcnt vmcnt(0)" ::: "memory");
      __builtin_amdgcn_s_barrier();
      __builtin_amdgcn_sched_barrier(0);
      compute(t & 3);
      __builtin_amdgcn_sched_barrier(0);
      __builtin_amdgcn_s_barrier();
      __builtin_amdgcn_sched_barrier(0);
    }
  };

  kloop(xb  + (size_t)bm * 256 * D_IN, D_IN, WbT + (size_t)bn * 256 * D_IN, D_IN, D_IN);
  kloop(C2b + (size_t)bm * 256 * KC2,  KC2,  BbT + (size_t)bn * 256 * KC2,  KC2,  KC2);

  float* Cb = out + (size_t)(bm * 256 + wm * 128) * O_OUT + bn * 256 + wn * 64;
  #pragma unroll
  for (int mi = 0; mi < 8; ++mi)
    #pragma unroll
    for (int nj = 0; nj < 4; ++nj)
      #pragma unroll
      for (int rg = 0; rg < 4; ++rg)
        Cb[(size_t)(mi * 16 + qd * 4 + rg) * O_OUT + nj * 16 + ln] = acc[mi][nj][rg];
}

// ---------------- launch ----------------
// ws layout (bytes):
//   xb    @ 0         : 33554432  (bf16 [4096,4096])
//   WbT   @ 33554432  : 33554432  (bf16 [4096,4096])
//   PabT  @ 67108864  : 2097152   (bf16 [256,4096])
//   BbT   @ 69206016  : 3145728   (bf16 [4096,384])
//   C2b   @ 72351744  : 3145728   (bf16 [4096,384])
//   gidx  @ 75497472  : 32768
//   gwv   @ 75530240  : 32768
// projP [4][4096][256] fp32 (16 MB) lives in d_out (dead until final GEMM overwrites).
extern "C" void kernel_launch(void* const* d_in, const int* in_sizes, int n_in,
                              void* d_out, int out_size, void* d_ws, size_t ws_size,
                              hipStream_t stream) {
  const float* x       = (const float*)d_in[0];
  const float* base_W  = (const float*)d_in[1];
  const float* routerW = (const float*)d_in[2];
  const float* A       = (const float*)d_in[3];
  const float* B       = (const float*)d_in[4];
  const float* Rm      = (const float*)d_in[5];
  float* out = (float*)d_out;
  char* ws = (char*)d_ws;

  bf16_t* xb   = (bf16_t*)(ws);
  bf16_t* WbT  = (bf16_t*)(ws + 33554432);
  bf16_t* PabT = (bf16_t*)(ws + 67108864);
  bf16_t* BbT  = (bf16_t*)(ws + 69206016);
  bf16_t* C2b  = (bf16_t*)(ws + 72351744);
  int*    gidx = (int*)   (ws + 75497472);
  float*  gwv  = (float*) (ws + 75530240);
  float*  projP = out;  // scratch: fully dead before gemm_fused writes out

  // 1) all independent prep in one saturating launch
  prep_kernel<<<5760, 256, 0, stream>>>(x, base_W, routerW, A, B, Rm,
                                        xb, WbT, BbT, PabT, gidx, gwv);
  // 2) proj split-K GEMM (non-atomic partials into d_out scratch)
  gemm_proj_kernel<<<dim3(32, 2, 4), 256, 0, stream>>>(xb, PabT, projP);
  // 3) gating -> C2 (sums 4 partials)
  gating_kernel<<<4096, 384, 0, stream>>>(projP, gidx, gwv, C2b);
  // 4) fused base+delta GEMM, 256^2 counted-vmcnt pipeline, single out write
  gemm_fused256<<<dim3(256), 512, 0, stream>>>(xb, WbT, C2b, BbT, out);
}

// Round 2
// 364.684 us; speedup vs baseline: 10.6041x; 10.6041x over previous
//
#include <hip/hip_runtime.h>
#include <hip/hip_bf16.h>
#include <math.h>

typedef __bf16 bf16_t;
typedef __bf16 bf16x4_t __attribute__((ext_vector_type(4)));
typedef __bf16 bf16x8_t __attribute__((ext_vector_type(8)));
typedef float  f32x4_t  __attribute__((ext_vector_type(4)));

#define N_TOK 4096
#define D_IN  4096
#define O_OUT 4096
#define NEXP  8
#define NHEAD 3
#define RANK  16
#define KC2   384      // E*H*R
#define PCOLS 256      // padded projection cols (152 used)
#define SCALING_F 2.0f

// ---------------- prep building blocks ----------------

// 64x64 transpose tile fp32 -> bf16, vectorized, <=2-way LDS aliasing (free).
__device__ __forceinline__ void transpose_tile(const float* __restrict__ src,
                                               bf16_t* __restrict__ dst,
                                               int Rr, int Cc, int r0, int c0,
                                               float (*tile)[65]) {
  int q  = threadIdx.x & 15;
  int r4 = threadIdx.x >> 4;
  #pragma unroll
  for (int g = 0; g < 4; ++g) {
    int r = r4 + g * 16;
    float4 v = *(const float4*)(src + (size_t)(r0 + r) * Cc + c0 + q * 4);
    tile[r][q * 4 + 0] = v.x; tile[r][q * 4 + 1] = v.y;
    tile[r][q * 4 + 2] = v.z; tile[r][q * 4 + 3] = v.w;
  }
  __syncthreads();
  #pragma unroll
  for (int g = 0; g < 4; ++g) {
    int c = r4 + g * 16;
    bf16x4_t o = { (bf16_t)tile[q * 4 + 0][c], (bf16_t)tile[q * 4 + 1][c],
                   (bf16_t)tile[q * 4 + 2][c], (bf16_t)tile[q * 4 + 3][c] };
    *(bf16x4_t*)(dst + (size_t)(c0 + c) * Rr + r0 + q * 4) = o;
  }
}

// ---------------- ONE prep kernel: all independent pre-GEMM work ----------------
__global__ __launch_bounds__(256) void prep_kernel(const float* __restrict__ x,
                                                   const float* __restrict__ base_W,
                                                   const float* __restrict__ rw,
                                                   const float* __restrict__ A,
                                                   const float* __restrict__ B,
                                                   const float* __restrict__ Rm,
                                                   bf16_t* __restrict__ xb,
                                                   bf16_t* __restrict__ WbT,
                                                   bf16_t* __restrict__ BbT,
                                                   bf16_t* __restrict__ PabT,
                                                   int* __restrict__ gidx,
                                                   float* __restrict__ gwv) {
  __shared__ float tile[64][65];
  int b = blockIdx.x;
  if (b < 4096) {
    transpose_tile(base_W, WbT, 4096, 4096, (b & 63) * 64, (b >> 6) * 64, tile);
  } else if (b < 5120) {
    int lane = threadIdx.x & 63;
    int wv = threadIdx.x >> 6;
    int n = (b - 4096) * 4 + wv;
    const float4* xv = (const float4*)(x + (size_t)n * D_IN);
    bf16x4_t* xo = (bf16x4_t*)(xb + (size_t)n * D_IN);
    float acc[NEXP] = {0, 0, 0, 0, 0, 0, 0, 0};
    for (int d = lane; d < D_IN / 4; d += 64) {
      float4 xx = xv[d];
      bf16x4_t ob = { (bf16_t)xx.x, (bf16_t)xx.y, (bf16_t)xx.z, (bf16_t)xx.w };
      xo[d] = ob;
      #pragma unroll
      for (int e = 0; e < NEXP; ++e) {
        float4 ww = ((const float4*)(rw + (size_t)e * D_IN))[d];
        acc[e] += xx.x * ww.x + xx.y * ww.y + xx.z * ww.z + xx.w * ww.w;
      }
    }
    #pragma unroll
    for (int e = 0; e < NEXP; ++e) {
      float v = acc[e];
      #pragma unroll
      for (int o = 32; o > 0; o >>= 1) v += __shfl_down(v, o);
      acc[e] = v;
    }
    if (lane == 0) {
      int i0 = 0; float l0 = acc[0];
      #pragma unroll
      for (int e = 1; e < NEXP; ++e) if (acc[e] > l0) { l0 = acc[e]; i0 = e; }
      int i1 = -1; float l1 = -3.4e38f;
      #pragma unroll
      for (int e = 0; e < NEXP; ++e) if (e != i0 && acc[e] > l1) { l1 = acc[e]; i1 = e; }
      float w0 = 1.f / (1.f + expf(l1 - l0));
      gidx[2 * n] = i0; gidx[2 * n + 1] = i1;
      gwv[2 * n] = w0;  gwv[2 * n + 1] = 1.f - w0;
    }
  } else if (b < 5504) {
    int t = b - 5120;
    transpose_tile(B, BbT, KC2, 4096, (t % 6) * 64, (t / 6) * 64, tile);
  } else {
    int c = b - 5504;  // 0..255: output row of PabT
    for (int d = threadIdx.x; d < D_IN; d += 256) {
      float v = 0.f;
      if (c < 128) {
        int e = c >> 4, r = c & 15;
        v = A[((size_t)e * D_IN + d) * RANK + r];
      } else if (c < 152) {
        int qq = c - 128; int e = qq / 3, h = qq - 3 * e;
        v = Rm[((size_t)e * D_IN + d) * NHEAD + h];
      }
      PabT[(size_t)c * D_IN + d] = (bf16_t)v;
    }
  }
}

// ---------------- gating: C2[n, e*48+h*16+r], summing 4 split-K partials ----------------
__global__ void gating_kernel(const float* __restrict__ projP, const int* __restrict__ gidx,
                              const float* __restrict__ gwv, bf16_t* __restrict__ C2b) {
  int n = blockIdx.x;
  int c = threadIdx.x;  // 0..383
  int e = c / 48;
  int h = (c % 48) / 16;
  int r = c & 15;
  int i0 = gidx[2 * n], i1 = gidx[2 * n + 1];
  float g = (e == i0) ? gwv[2 * n] : (e == i1) ? gwv[2 * n + 1] : 0.f;
  float val = 0.f;
  if (g != 0.f) {
    const float* p0 = projP + (size_t)n * PCOLS;
    const size_t S = (size_t)N_TOK * PCOLS;
    #define RD(cc) (p0[(cc)] + p0[(cc) + S] + p0[(cc) + 2 * S] + p0[(cc) + 3 * S])
    float h0 = RD(128 + e * 3 + 0);
    float h1 = RD(128 + e * 3 + 1);
    float h2 = RD(128 + e * 3 + 2);
    float av = RD(e * 16 + r);
    #undef RD
    float mx = fmaxf(h0, fmaxf(h1, h2));
    float e0 = expf(h0 - mx), e1 = expf(h1 - mx), e2 = expf(h2 - mx);
    float hw = (h == 0 ? e0 : h == 1 ? e1 : e2) / (e0 + e1 + e2);
    val = SCALING_F * g * hw * av;
  }
  C2b[(size_t)n * KC2 + c] = (bf16_t)val;
}

// ---------------- m97-style MFMA K-loop core (used by proj GEMM only) ----------------
__device__ __forceinline__ void run_kloop(f32x4_t (&acc)[4][4], bf16_t* sA, bf16_t* sB,
                                          const bf16_t* __restrict__ Ab, int lda,
                                          const bf16_t* __restrict__ Bb, int ldb, int K) {
  const int tid = threadIdx.x;
  const int lane = tid & 63;
  const int w = tid >> 6;
  const int wm = (w >> 1) * 64;
  const int wn = (w & 1) * 64;
  const int qd = lane >> 4;
  const int ln = lane & 15;
  const int sw = ln & 7;

  size_t offA[4], offB[4];
  int lo[4];
  #pragma unroll
  for (int t = 0; t < 4; ++t) {
    int c = tid + t * 256;
    int m = c >> 3, kc = (c & 7) ^ (m & 7);
    offA[t] = (size_t)m * lda + kc * 8;
    offB[t] = (size_t)m * ldb + kc * 8;
    lo[t] = c * 8;
  }
  int rowA[4], rowB[4];
  #pragma unroll
  for (int i = 0; i < 4; ++i) {
    rowA[i] = (wm + i * 16 + ln) * 64;
    rowB[i] = (wn + i * 16 + ln) * 64;
  }

  for (int k0 = 0; k0 < K; k0 += 64) {
    __syncthreads();
    #pragma unroll
    for (int t = 0; t < 4; ++t)
      __builtin_amdgcn_global_load_lds(
          (const __attribute__((address_space(1))) void*)(Ab + k0 + offA[t]),
          (__attribute__((address_space(3))) void*)(sA + lo[t]), 16, 0, 0);
    #pragma unroll
    for (int t = 0; t < 4; ++t)
      __builtin_amdgcn_global_load_lds(
          (const __attribute__((address_space(1))) void*)(Bb + k0 + offB[t]),
          (__attribute__((address_space(3))) void*)(sB + lo[t]), 16, 0, 0);
    __syncthreads();
    #pragma unroll
    for (int s = 0; s < 2; ++s) {
      bf16x8_t af[4], bfr[4];
      int kx = ((s * 4 + qd) ^ sw) * 8;
      #pragma unroll
      for (int i = 0; i < 4; ++i) af[i]  = *(const bf16x8_t*)(sA + rowA[i] + kx);
      #pragma unroll
      for (int i = 0; i < 4; ++i) bfr[i] = *(const bf16x8_t*)(sB + rowB[i] + kx);
      #pragma unroll
      for (int i = 0; i < 4; ++i)
        #pragma unroll
        for (int j = 0; j < 4; ++j)
          acc[i][j] = __builtin_amdgcn_mfma_f32_16x16x32_bf16(af[i], bfr[j], acc[i][j], 0, 0, 0);
    }
  }
}

// proj split-K GEMM: projP[kz][4096,256] = xb @ PabT^T partial (K slice 1024), plain stores.
__global__ __launch_bounds__(256) void gemm_proj_kernel(const bf16_t* __restrict__ xb,
                                                        const bf16_t* __restrict__ PabT,
                                                        float* __restrict__ projP) {
  __shared__ bf16_t sA[128 * 64];
  __shared__ bf16_t sB[128 * 64];
  int bm = blockIdx.x, bn = blockIdx.y, kz = blockIdx.z;
  f32x4_t acc[4][4] = {};
  run_kloop(acc, sA, sB,
            xb + (size_t)bm * 128 * D_IN + kz * 1024, D_IN,
            PabT + (size_t)bn * 128 * D_IN + kz * 1024, D_IN, 1024);
  const int lane = threadIdx.x & 63, w = threadIdx.x >> 6;
  const int wm = (w >> 1) * 64, wn = (w & 1) * 64, qd = lane >> 4, ln = lane & 15;
  float* Cb = projP + (size_t)kz * N_TOK * PCOLS + (size_t)bm * 128 * PCOLS + bn * 128;
  #pragma unroll
  for (int i = 0; i < 4; ++i)
    #pragma unroll
    for (int j = 0; j < 4; ++j) {
      int col = wn + j * 16 + ln;
      #pragma unroll
      for (int rg = 0; rg < 4; ++rg) {
        int row = wm + i * 16 + qd * 4 + rg;
        Cb[(size_t)row * PCOLS + col] = acc[i][j][rg];
      }
    }
}

// ---------------- fused big GEMM, 256x256 tile, BK=32, ring-4 counted-vmcnt pipeline ----
// Same schedule as round 1 (correctness-verified), restructured as plain __forceinline__
// functions with reference args (run_kloop pattern) so acc/af/bv stay in registers.
// NO lambdas: round-1's [&]-capturing lambdas + asm-"memory" defeated SROA -> acc went to
// scratch (VGPR_Count 88, WRITE_SIZE 9.3 GB of spill traffic, MfmaUtil 1.7%).

__device__ __forceinline__ void stage256(const bf16_t* __restrict__ G, int ld, int k0,
                                         bf16_t* lbase, int tid) {
  #pragma unroll
  for (int r = 0; r < 2; ++r) {
    int s = r * 512 + tid;               // 16B slot: row = s>>2, chunk' = s&3
    int row = s >> 2;
    int c = (s & 3) ^ ((row >> 1) & 3);  // inverse-swizzled source chunk (rule 21)
    __builtin_amdgcn_global_load_lds(
        (const __attribute__((address_space(1))) void*)(G + (size_t)row * ld + k0 + c * 8),
        (__attribute__((address_space(3))) void*)(lbase + s * 8), 16, 0, 0);
  }
}

__device__ __forceinline__ void compute256(f32x4_t (&acc)[8][4],
                                           const bf16_t* pA, const bf16_t* pB) {
  bf16x8_t af[8], bv[4];
  #pragma unroll
  for (int nj = 0; nj < 4; ++nj) bv[nj] = *(const bf16x8_t*)(pB + nj * 512);
  #pragma unroll
  for (int mi = 0; mi < 8; ++mi) af[mi] = *(const bf16x8_t*)(pA + mi * 512);
  __builtin_amdgcn_s_setprio(1);
  #pragma unroll
  for (int mi = 0; mi < 8; ++mi)
    #pragma unroll
    for (int nj = 0; nj < 4; ++nj)
      acc[mi][nj] = __builtin_amdgcn_mfma_f32_16x16x32_bf16(af[mi], bv[nj], acc[mi][nj], 0, 0, 0);
  __builtin_amdgcn_s_setprio(0);
}

// Schedule per K-tile t (main loop):
//   issue A-stage of tile t+3 (2 glds)   // slot (t+3)&3 == (t-1)&3, free since end-bar(t-1)
//   s_waitcnt vmcnt(10)                  // tile t fully landed; t+1,t+2,t+3A stay in flight
//   s_barrier                            // all waves' tile-t LDS visible
//   issue B-stage of tile t+3 (2 glds)   // interleaves with compute
//   12x ds_read_b128 (swizzled, conflict-free) + setprio(1) 32x MFMA setprio(0)
//   s_barrier                            // reads of slot t&3 done -> re-stageable
__device__ __forceinline__ void kloop256(f32x4_t (&acc)[8][4], bf16_t* sring,
                                         const bf16_t* __restrict__ A, int lda,
                                         const bf16_t* __restrict__ B, int ldb,
                                         int K, int tid, int aoff, int boff) {
  const int T = K / 32;                   // 128 and 12 at the two call sites
  #pragma unroll
  for (int t = 0; t < 3; ++t) {           // prologue: tiles 0..2 -> slots 0..2 (12 glds)
    stage256(A, lda, t * 32, sring + t * 16384, tid);
    stage256(B, ldb, t * 32, sring + t * 16384 + 8192, tid);
  }
  for (int t = 0; t < T - 3; ++t) {
    const int k3 = (t + 3) * 32;
    const int s3 = (t + 3) & 3;
    const int sc = t & 3;
    stage256(A, lda, k3, sring + s3 * 16384, tid);       // 12 -> 14 outstanding
    asm volatile("s_waitcnt vmcnt(10)" ::: "memory");    // tile t landed (per wave)
    __builtin_amdgcn_s_barrier();
    __builtin_amdgcn_sched_barrier(0);
    stage256(B, ldb, k3, sring + s3 * 16384 + 8192, tid);
    compute256(acc, sring + sc * 16384 + aoff, sring + sc * 16384 + 8192 + boff);
    __builtin_amdgcn_sched_barrier(0);
    __builtin_amdgcn_s_barrier();                        // slot sc reads done
    __builtin_amdgcn_sched_barrier(0);
  }
  #pragma unroll 1
  for (int t = T - 3; t < T; ++t) {       // tail: drain 8 -> 4 -> 0
    const int rem = T - t;
    if (rem == 3)      asm volatile("s_waitcnt vmcnt(8)" ::: "memory");
    else if (rem == 2) asm volatile("s_waitcnt vmcnt(4)" ::: "memory");
    else               asm volatile("s_waitcnt vmcnt(0)" ::: "memory");
    __builtin_amdgcn_s_barrier();
    __builtin_amdgcn_sched_barrier(0);
    compute256(acc, sring + (t & 3) * 16384 + aoff, sring + (t & 3) * 16384 + 8192 + boff);
    __builtin_amdgcn_sched_barrier(0);
    __builtin_amdgcn_s_barrier();
    __builtin_amdgcn_sched_barrier(0);
  }
}

// 512 threads = 8 waves (2 M-groups x 4 N-groups); per-wave output 128x64.
// LDS: 4-slot ring x (A 16KB + B 16KB) = 128 KiB -> occupancy is LDS-bound at 1 block/CU
// (2 waves/SIMD), so __launch_bounds__ min-waves=1: no artificial VGPR cap, no spill.
__global__ __launch_bounds__(512, 1) void gemm_fused256(const bf16_t* __restrict__ xb,
                                                        const bf16_t* __restrict__ WbT,
                                                        const bf16_t* __restrict__ C2b,
                                                        const bf16_t* __restrict__ BbT,
                                                        float* __restrict__ out) {
  __shared__ __align__(16) bf16_t sring[4 * 16384];  // [slot][A 8192 | B 8192]
  const int tid = threadIdx.x;
  const int lane = tid & 63;
  const int w = tid >> 6;
  const int wm = w >> 2;          // 0..1
  const int wn = w & 3;           // 0..3
  const int qd = lane >> 4;       // k-chunk
  const int ln = lane & 15;       // row-in-frag
  const int swz8 = ((qd ^ ((ln >> 1) & 3)) << 3);  // swizzled k-chunk, elem units

  // XCD-aware bijective swizzle (256 blocks, 256 % 8 == 0)
  int b = blockIdx.x;
  int sw = (b & 7) * 32 + (b >> 3);
  int bm = sw >> 4, bn = sw & 15;

  const int aoff = (wm * 128 + ln) * 32 + swz8;
  const int boff = (wn * 64 + ln) * 32 + swz8;

  f32x4_t acc[8][4] = {};

  kloop256(acc, sring, xb  + (size_t)bm * 256 * D_IN, D_IN,
                       WbT + (size_t)bn * 256 * D_IN, D_IN, D_IN, tid, aoff, boff);
  kloop256(acc, sring, C2b + (size_t)bm * 256 * KC2,  KC2,
                       BbT + (size_t)bn * 256 * KC2,  KC2,  KC2,  tid, aoff, boff);

  float* Cb = out + (size_t)(bm * 256 + wm * 128) * O_OUT + bn * 256 + wn * 64;
  #pragma unroll
  for (int mi = 0; mi < 8; ++mi)
    #pragma unroll
    for (int nj = 0; nj < 4; ++nj)
      #pragma unroll
      for (int rg = 0; rg < 4; ++rg)
        Cb[(size_t)(mi * 16 + qd * 4 + rg) * O_OUT + nj * 16 + ln] = acc[mi][nj][rg];
}

// ---------------- launch ----------------
// ws layout (bytes):
//   xb    @ 0         : 33554432  (bf16 [4096,4096])
//   WbT   @ 33554432  : 33554432  (bf16 [4096,4096])
//   PabT  @ 67108864  : 2097152   (bf16 [256,4096])
//   BbT   @ 69206016  : 3145728   (bf16 [4096,384])
//   C2b   @ 72351744  : 3145728   (bf16 [4096,384])
//   gidx  @ 75497472  : 32768
//   gwv   @ 75530240  : 32768
// projP [4][4096][256] fp32 (16 MB) lives in d_out (dead until final GEMM overwrites).
extern "C" void kernel_launch(void* const* d_in, const int* in_sizes, int n_in,
                              void* d_out, int out_size, void* d_ws, size_t ws_size,
                              hipStream_t stream) {
  const float* x       = (const float*)d_in[0];
  const float* base_W  = (const float*)d_in[1];
  const float* routerW = (const float*)d_in[2];
  const float* A       = (const float*)d_in[3];
  const float* B       = (const float*)d_in[4];
  const float* Rm      = (const float*)d_in[5];
  float* out = (float*)d_out;
  char* ws = (char*)d_ws;

  bf16_t* xb   = (bf16_t*)(ws);
  bf16_t* WbT  = (bf16_t*)(ws + 33554432);
  bf16_t* PabT = (bf16_t*)(ws + 67108864);
  bf16_t* BbT  = (bf16_t*)(ws + 69206016);
  bf16_t* C2b  = (bf16_t*)(ws + 72351744);
  int*    gidx = (int*)   (ws + 75497472);
  float*  gwv  = (float*) (ws + 75530240);
  float*  projP = out;  // scratch: fully dead before gemm_fused writes out

  // 1) all independent prep in one saturating launch
  prep_kernel<<<5760, 256, 0, stream>>>(x, base_W, routerW, A, B, Rm,
                                        xb, WbT, BbT, PabT, gidx, gwv);
  // 2) proj split-K GEMM (non-atomic partials into d_out scratch)
  gemm_proj_kernel<<<dim3(32, 2, 4), 256, 0, stream>>>(xb, PabT, projP);
  // 3) gating -> C2 (sums 4 partials)
  gating_kernel<<<4096, 384, 0, stream>>>(projP, gidx, gwv, C2b);
  // 4) fused base+delta GEMM, 256^2 counted-vmcnt pipeline, single out write
  gemm_fused256<<<dim3(256), 512, 0, stream>>>(xb, WbT, C2b, BbT, out);
}

// Round 3
// 363.850 us; speedup vs baseline: 10.6284x; 1.0023x over previous
//
#include <hip/hip_runtime.h>
#include <hip/hip_bf16.h>
#include <math.h>

typedef __bf16 bf16_t;
typedef __bf16 bf16x4_t __attribute__((ext_vector_type(4)));
typedef __bf16 bf16x8_t __attribute__((ext_vector_type(8)));
typedef float  f32x4_t  __attribute__((ext_vector_type(4)));

#define N_TOK 4096
#define D_IN  4096
#define O_OUT 4096
#define NEXP  8
#define NHEAD 3
#define RANK  16
#define KC2   384      // E*H*R
#define PCOLS 256      // padded projection cols (152 used)
#define SCALING_F 2.0f

// ---------------- prep building blocks ----------------

// 64x64 transpose tile fp32 -> bf16, vectorized, <=2-way LDS aliasing (free).
__device__ __forceinline__ void transpose_tile(const float* __restrict__ src,
                                               bf16_t* __restrict__ dst,
                                               int Rr, int Cc, int r0, int c0,
                                               float (*tile)[65]) {
  int q  = threadIdx.x & 15;
  int r4 = threadIdx.x >> 4;
  #pragma unroll
  for (int g = 0; g < 4; ++g) {
    int r = r4 + g * 16;
    float4 v = *(const float4*)(src + (size_t)(r0 + r) * Cc + c0 + q * 4);
    tile[r][q * 4 + 0] = v.x; tile[r][q * 4 + 1] = v.y;
    tile[r][q * 4 + 2] = v.z; tile[r][q * 4 + 3] = v.w;
  }
  __syncthreads();
  #pragma unroll
  for (int g = 0; g < 4; ++g) {
    int c = r4 + g * 16;
    bf16x4_t o = { (bf16_t)tile[q * 4 + 0][c], (bf16_t)tile[q * 4 + 1][c],
                   (bf16_t)tile[q * 4 + 2][c], (bf16_t)tile[q * 4 + 3][c] };
    *(bf16x4_t*)(dst + (size_t)(c0 + c) * Rr + r0 + q * 4) = o;
  }
}

// ---------------- ONE prep kernel: all independent pre-GEMM work ----------------
__global__ __launch_bounds__(256) void prep_kernel(const float* __restrict__ x,
                                                   const float* __restrict__ base_W,
                                                   const float* __restrict__ rw,
                                                   const float* __restrict__ A,
                                                   const float* __restrict__ B,
                                                   const float* __restrict__ Rm,
                                                   bf16_t* __restrict__ xb,
                                                   bf16_t* __restrict__ WbT,
                                                   bf16_t* __restrict__ BbT,
                                                   bf16_t* __restrict__ PabT,
                                                   int* __restrict__ gidx,
                                                   float* __restrict__ gwv) {
  __shared__ float tile[64][65];
  int b = blockIdx.x;
  if (b < 4096) {
    transpose_tile(base_W, WbT, 4096, 4096, (b & 63) * 64, (b >> 6) * 64, tile);
  } else if (b < 5120) {
    int lane = threadIdx.x & 63;
    int wv = threadIdx.x >> 6;
    int n = (b - 4096) * 4 + wv;
    const float4* xv = (const float4*)(x + (size_t)n * D_IN);
    bf16x4_t* xo = (bf16x4_t*)(xb + (size_t)n * D_IN);
    float acc[NEXP] = {0, 0, 0, 0, 0, 0, 0, 0};
    for (int d = lane; d < D_IN / 4; d += 64) {
      float4 xx = xv[d];
      bf16x4_t ob = { (bf16_t)xx.x, (bf16_t)xx.y, (bf16_t)xx.z, (bf16_t)xx.w };
      xo[d] = ob;
      #pragma unroll
      for (int e = 0; e < NEXP; ++e) {
        float4 ww = ((const float4*)(rw + (size_t)e * D_IN))[d];
        acc[e] += xx.x * ww.x + xx.y * ww.y + xx.z * ww.z + xx.w * ww.w;
      }
    }
    #pragma unroll
    for (int e = 0; e < NEXP; ++e) {
      float v = acc[e];
      #pragma unroll
      for (int o = 32; o > 0; o >>= 1) v += __shfl_down(v, o);
      acc[e] = v;
    }
    if (lane == 0) {
      int i0 = 0; float l0 = acc[0];
      #pragma unroll
      for (int e = 1; e < NEXP; ++e) if (acc[e] > l0) { l0 = acc[e]; i0 = e; }
      int i1 = -1; float l1 = -3.4e38f;
      #pragma unroll
      for (int e = 0; e < NEXP; ++e) if (e != i0 && acc[e] > l1) { l1 = acc[e]; i1 = e; }
      float w0 = 1.f / (1.f + expf(l1 - l0));
      gidx[2 * n] = i0; gidx[2 * n + 1] = i1;
      gwv[2 * n] = w0;  gwv[2 * n + 1] = 1.f - w0;
    }
  } else if (b < 5504) {
    int t = b - 5120;
    transpose_tile(B, BbT, KC2, 4096, (t % 6) * 64, (t / 6) * 64, tile);
  } else {
    int c = b - 5504;  // 0..255: output row of PabT
    for (int d = threadIdx.x; d < D_IN; d += 256) {
      float v = 0.f;
      if (c < 128) {
        int e = c >> 4, r = c & 15;
        v = A[((size_t)e * D_IN + d) * RANK + r];
      } else if (c < 152) {
        int qq = c - 128; int e = qq / 3, h = qq - 3 * e;
        v = Rm[((size_t)e * D_IN + d) * NHEAD + h];
      }
      PabT[(size_t)c * D_IN + d] = (bf16_t)v;
    }
  }
}

// ---------------- gating: C2[n, e*48+h*16+r], summing 4 split-K partials ----------------
__global__ void gating_kernel(const float* __restrict__ projP, const int* __restrict__ gidx,
                              const float* __restrict__ gwv, bf16_t* __restrict__ C2b) {
  int n = blockIdx.x;
  int c = threadIdx.x;  // 0..383
  int e = c / 48;
  int h = (c % 48) / 16;
  int r = c & 15;
  int i0 = gidx[2 * n], i1 = gidx[2 * n + 1];
  float g = (e == i0) ? gwv[2 * n] : (e == i1) ? gwv[2 * n + 1] : 0.f;
  float val = 0.f;
  if (g != 0.f) {
    const float* p0 = projP + (size_t)n * PCOLS;
    const size_t S = (size_t)N_TOK * PCOLS;
    #define RD(cc) (p0[(cc)] + p0[(cc) + S] + p0[(cc) + 2 * S] + p0[(cc) + 3 * S])
    float h0 = RD(128 + e * 3 + 0);
    float h1 = RD(128 + e * 3 + 1);
    float h2 = RD(128 + e * 3 + 2);
    float av = RD(e * 16 + r);
    #undef RD
    float mx = fmaxf(h0, fmaxf(h1, h2));
    float e0 = expf(h0 - mx), e1 = expf(h1 - mx), e2 = expf(h2 - mx);
    float hw = (h == 0 ? e0 : h == 1 ? e1 : e2) / (e0 + e1 + e2);
    val = SCALING_F * g * hw * av;
  }
  C2b[(size_t)n * KC2 + c] = (bf16_t)val;
}

// ---------------- m97-style MFMA K-loop core (used by proj GEMM only) ----------------
__device__ __forceinline__ void run_kloop(f32x4_t (&acc)[4][4], bf16_t* sA, bf16_t* sB,
                                          const bf16_t* __restrict__ Ab, int lda,
                                          const bf16_t* __restrict__ Bb, int ldb, int K) {
  const int tid = threadIdx.x;
  const int lane = tid & 63;
  const int w = tid >> 6;
  const int wm = (w >> 1) * 64;
  const int wn = (w & 1) * 64;
  const int qd = lane >> 4;
  const int ln = lane & 15;
  const int sw = ln & 7;

  size_t offA[4], offB[4];
  int lo[4];
  #pragma unroll
  for (int t = 0; t < 4; ++t) {
    int c = tid + t * 256;
    int m = c >> 3, kc = (c & 7) ^ (m & 7);
    offA[t] = (size_t)m * lda + kc * 8;
    offB[t] = (size_t)m * ldb + kc * 8;
    lo[t] = c * 8;
  }
  int rowA[4], rowB[4];
  #pragma unroll
  for (int i = 0; i < 4; ++i) {
    rowA[i] = (wm + i * 16 + ln) * 64;
    rowB[i] = (wn + i * 16 + ln) * 64;
  }

  for (int k0 = 0; k0 < K; k0 += 64) {
    __syncthreads();
    #pragma unroll
    for (int t = 0; t < 4; ++t)
      __builtin_amdgcn_global_load_lds(
          (const __attribute__((address_space(1))) void*)(Ab + k0 + offA[t]),
          (__attribute__((address_space(3))) void*)(sA + lo[t]), 16, 0, 0);
    #pragma unroll
    for (int t = 0; t < 4; ++t)
      __builtin_amdgcn_global_load_lds(
          (const __attribute__((address_space(1))) void*)(Bb + k0 + offB[t]),
          (__attribute__((address_space(3))) void*)(sB + lo[t]), 16, 0, 0);
    __syncthreads();
    #pragma unroll
    for (int s = 0; s < 2; ++s) {
      bf16x8_t af[4], bfr[4];
      int kx = ((s * 4 + qd) ^ sw) * 8;
      #pragma unroll
      for (int i = 0; i < 4; ++i) af[i]  = *(const bf16x8_t*)(sA + rowA[i] + kx);
      #pragma unroll
      for (int i = 0; i < 4; ++i) bfr[i] = *(const bf16x8_t*)(sB + rowB[i] + kx);
      #pragma unroll
      for (int i = 0; i < 4; ++i)
        #pragma unroll
        for (int j = 0; j < 4; ++j)
          acc[i][j] = __builtin_amdgcn_mfma_f32_16x16x32_bf16(af[i], bfr[j], acc[i][j], 0, 0, 0);
    }
  }
}

// proj split-K GEMM: projP[kz][4096,256] = xb @ PabT^T partial (K slice 1024), plain stores.
__global__ __launch_bounds__(256) void gemm_proj_kernel(const bf16_t* __restrict__ xb,
                                                        const bf16_t* __restrict__ PabT,
                                                        float* __restrict__ projP) {
  __shared__ bf16_t sA[128 * 64];
  __shared__ bf16_t sB[128 * 64];
  int bm = blockIdx.x, bn = blockIdx.y, kz = blockIdx.z;
  f32x4_t acc[4][4] = {};
  run_kloop(acc, sA, sB,
            xb + (size_t)bm * 128 * D_IN + kz * 1024, D_IN,
            PabT + (size_t)bn * 128 * D_IN + kz * 1024, D_IN, 1024);
  const int lane = threadIdx.x & 63, w = threadIdx.x >> 6;
  const int wm = (w >> 1) * 64, wn = (w & 1) * 64, qd = lane >> 4, ln = lane & 15;
  float* Cb = projP + (size_t)kz * N_TOK * PCOLS + (size_t)bm * 128 * PCOLS + bn * 128;
  #pragma unroll
  for (int i = 0; i < 4; ++i)
    #pragma unroll
    for (int j = 0; j < 4; ++j) {
      int col = wn + j * 16 + ln;
      #pragma unroll
      for (int rg = 0; rg < 4; ++rg) {
        int row = wm + i * 16 + qd * 4 + rg;
        Cb[(size_t)row * PCOLS + col] = acc[i][j][rg];
      }
    }
}

// ---------------- fused big GEMM, 256x256 tile, BK=32, ring-4 counted-vmcnt pipeline ----
// Round-3 change: each K-tile's compute is split into TWO barrier-separated half-phases
// (T3 role-split -> T5 setprio pays; m218b). Staging invariants, vmcnt arithmetic
// (14->10 main, 8/4/0 tail), swizzle: identical to the round-2 correctness-proven kernel.

__device__ __forceinline__ void stage256(const bf16_t* __restrict__ G, int ld, int k0,
                                         bf16_t* lbase, int tid) {
  #pragma unroll
  for (int r = 0; r < 2; ++r) {
    int s = r * 512 + tid;               // 16B slot: row = s>>2, chunk' = s&3
    int row = s >> 2;
    int c = (s & 3) ^ ((row >> 1) & 3);  // inverse-swizzled source chunk (rule 21)
    __builtin_amdgcn_global_load_lds(
        (const __attribute__((address_space(1))) void*)(G + (size_t)row * ld + k0 + c * 8),
        (__attribute__((address_space(3))) void*)(lbase + s * 8), 16, 0, 0);
  }
}

// one 16-MFMA quadrant cluster, acc rows MB..MB+3 (MB is a compile-time constant)
template <int MB>
__device__ __forceinline__ void mfma16(f32x4_t (&acc)[8][4], const bf16x8_t (&af)[4],
                                       const bf16x8_t (&bv)[4]) {
  __builtin_amdgcn_s_setprio(1);
  #pragma unroll
  for (int mi = 0; mi < 4; ++mi)
    #pragma unroll
    for (int nj = 0; nj < 4; ++nj)
      acc[MB + mi][nj] =
          __builtin_amdgcn_mfma_f32_16x16x32_bf16(af[mi], bv[nj], acc[MB + mi][nj], 0, 0, 0);
  __builtin_amdgcn_s_setprio(0);
}

// monolithic 12-read/32-MFMA compute (prologue-free tail iterations only)
__device__ __forceinline__ void compute256(f32x4_t (&acc)[8][4],
                                           const bf16_t* pA, const bf16_t* pB) {
  bf16x8_t af[8], bv[4];
  #pragma unroll
  for (int nj = 0; nj < 4; ++nj) bv[nj] = *(const bf16x8_t*)(pB + nj * 512);
  #pragma unroll
  for (int mi = 0; mi < 8; ++mi) af[mi] = *(const bf16x8_t*)(pA + mi * 512);
  __builtin_amdgcn_s_setprio(1);
  #pragma unroll
  for (int mi = 0; mi < 8; ++mi)
    #pragma unroll
    for (int nj = 0; nj < 4; ++nj)
      acc[mi][nj] = __builtin_amdgcn_mfma_f32_16x16x32_bf16(af[mi], bv[nj], acc[mi][nj], 0, 0, 0);
  __builtin_amdgcn_s_setprio(0);
}

// Main-loop schedule per K-tile t:
//   stage A(t+3)                       // slot (t+3)&3 free since end-bar(t-1)
//   s_waitcnt vmcnt(10); s_barrier     // tile t landed + visible
//   ph_a: read B[0..3]+A[0..3] (8 ds) ; stage B(t+3) ; lgkmcnt(0) ; 16 MFMA (mi 0..3)
//   read A[4..7] (4 ds, issued pre-barrier: latency hides under barrier+other waves)
//   s_barrier (mid, role-split)
//   ph_b: lgkmcnt(0) ; 16 MFMA (mi 4..7)
//   s_barrier (end: slot t&3 reads done -> re-stageable)
__device__ __forceinline__ void kloop256(f32x4_t (&acc)[8][4], bf16_t* sring,
                                         const bf16_t* __restrict__ A, int lda,
                                         const bf16_t* __restrict__ B, int ldb,
                                         int K, int tid, int aoff, int boff) {
  const int T = K / 32;                   // 128 and 12 at the two call sites
  #pragma unroll
  for (int t = 0; t < 3; ++t) {           // prologue: tiles 0..2 -> slots 0..2 (12 glds)
    stage256(A, lda, t * 32, sring + t * 16384, tid);
    stage256(B, ldb, t * 32, sring + t * 16384 + 8192, tid);
  }
  for (int t = 0; t < T - 3; ++t) {
    const int k3 = (t + 3) * 32;
    const int s3 = (t + 3) & 3;
    const int sc = t & 3;
    stage256(A, lda, k3, sring + s3 * 16384, tid);       // 12 -> 14 outstanding
    asm volatile("s_waitcnt vmcnt(10)" ::: "memory");    // tile t landed (per wave)
    __builtin_amdgcn_s_barrier();
    __builtin_amdgcn_sched_barrier(0);
    const bf16_t* pA = sring + sc * 16384 + aoff;
    const bf16_t* pB = sring + sc * 16384 + 8192 + boff;
    bf16x8_t bv[4], a0[4], a1[4];
    #pragma unroll
    for (int nj = 0; nj < 4; ++nj) bv[nj] = *(const bf16x8_t*)(pB + nj * 512);
    #pragma unroll
    for (int mi = 0; mi < 4; ++mi) a0[mi] = *(const bf16x8_t*)(pA + mi * 512);
    stage256(B, ldb, k3, sring + s3 * 16384 + 8192, tid);
    asm volatile("s_waitcnt lgkmcnt(0)" ::: "memory");
    __builtin_amdgcn_sched_barrier(0);
    mfma16<0>(acc, a0, bv);
    #pragma unroll
    for (int mi = 0; mi < 4; ++mi) a1[mi] = *(const bf16x8_t*)(pA + (4 + mi) * 512);
    __builtin_amdgcn_sched_barrier(0);
    __builtin_amdgcn_s_barrier();                        // mid barrier: role split
    __builtin_amdgcn_sched_barrier(0);
    asm volatile("s_waitcnt lgkmcnt(0)" ::: "memory");
    __builtin_amdgcn_sched_barrier(0);
    mfma16<4>(acc, a1, bv);
    __builtin_amdgcn_sched_barrier(0);
    __builtin_amdgcn_s_barrier();                        // slot sc reads done
    __builtin_amdgcn_sched_barrier(0);
  }
  #pragma unroll 1
  for (int t = T - 3; t < T; ++t) {       // tail: drain 8 -> 4 -> 0
    const int rem = T - t;
    if (rem == 3)      asm volatile("s_waitcnt vmcnt(8)" ::: "memory");
    else if (rem == 2) asm volatile("s_waitcnt vmcnt(4)" ::: "memory");
    else               asm volatile("s_waitcnt vmcnt(0)" ::: "memory");
    __builtin_amdgcn_s_barrier();
    __builtin_amdgcn_sched_barrier(0);
    compute256(acc, sring + (t & 3) * 16384 + aoff, sring + (t & 3) * 16384 + 8192 + boff);
    __builtin_amdgcn_sched_barrier(0);
    __builtin_amdgcn_s_barrier();
    __builtin_amdgcn_sched_barrier(0);
  }
}

// 512 threads = 8 waves (2 M-groups x 4 N-groups); per-wave output 128x64.
// LDS: 4-slot ring x (A 16KB + B 16KB) = 128 KiB -> occupancy LDS-bound at 1 block/CU.
__global__ __launch_bounds__(512, 1) void gemm_fused256(const bf16_t* __restrict__ xb,
                                                        const bf16_t* __restrict__ WbT,
                                                        const bf16_t* __restrict__ C2b,
                                                        const bf16_t* __restrict__ BbT,
                                                        float* __restrict__ out) {
  __shared__ __align__(16) bf16_t sring[4 * 16384];  // [slot][A 8192 | B 8192]
  const int tid = threadIdx.x;
  const int lane = tid & 63;
  const int w = tid >> 6;
  const int wm = w >> 2;          // 0..1
  const int wn = w & 3;           // 0..3
  const int qd = lane >> 4;       // k-chunk
  const int ln = lane & 15;       // row-in-frag
  const int swz8 = ((qd ^ ((ln >> 1) & 3)) << 3);  // swizzled k-chunk, elem units

  // XCD-aware bijective swizzle (256 blocks, 256 % 8 == 0)
  int b = blockIdx.x;
  int sw = (b & 7) * 32 + (b >> 3);
  int bm = sw >> 4, bn = sw & 15;

  const int aoff = (wm * 128 + ln) * 32 + swz8;
  const int boff = (wn * 64 + ln) * 32 + swz8;

  f32x4_t acc[8][4] = {};

  kloop256(acc, sring, xb  + (size_t)bm * 256 * D_IN, D_IN,
                       WbT + (size_t)bn * 256 * D_IN, D_IN, D_IN, tid, aoff, boff);
  kloop256(acc, sring, C2b + (size_t)bm * 256 * KC2,  KC2,
                       BbT + (size_t)bn * 256 * KC2,  KC2,  KC2,  tid, aoff, boff);

  float* Cb = out + (size_t)(bm * 256 + wm * 128) * O_OUT + bn * 256 + wn * 64;
  #pragma unroll
  for (int mi = 0; mi < 8; ++mi)
    #pragma unroll
    for (int nj = 0; nj < 4; ++nj)
      #pragma unroll
      for (int rg = 0; rg < 4; ++rg)
        Cb[(size_t)(mi * 16 + qd * 4 + rg) * O_OUT + nj * 16 + ln] = acc[mi][nj][rg];
}

// ---------------- launch ----------------
// ws layout (bytes):
//   xb    @ 0         : 33554432  (bf16 [4096,4096])
//   WbT   @ 33554432  : 33554432  (bf16 [4096,4096])
//   PabT  @ 67108864  : 2097152   (bf16 [256,4096])
//   BbT   @ 69206016  : 3145728   (bf16 [4096,384])
//   C2b   @ 72351744  : 3145728   (bf16 [4096,384])
//   gidx  @ 75497472  : 32768
//   gwv   @ 75530240  : 32768
// projP [4][4096][256] fp32 (16 MB) lives in d_out (dead until final GEMM overwrites).
extern "C" void kernel_launch(void* const* d_in, const int* in_sizes, int n_in,
                              void* d_out, int out_size, void* d_ws, size_t ws_size,
                              hipStream_t stream) {
  const float* x       = (const float*)d_in[0];
  const float* base_W  = (const float*)d_in[1];
  const float* routerW = (const float*)d_in[2];
  const float* A       = (const float*)d_in[3];
  const float* B       = (const float*)d_in[4];
  const float* Rm      = (const float*)d_in[5];
  float* out = (float*)d_out;
  char* ws = (char*)d_ws;

  bf16_t* xb   = (bf16_t*)(ws);
  bf16_t* WbT  = (bf16_t*)(ws + 33554432);
  bf16_t* PabT = (bf16_t*)(ws + 67108864);
  bf16_t* BbT  = (bf16_t*)(ws + 69206016);
  bf16_t* C2b  = (bf16_t*)(ws + 72351744);
  int*    gidx = (int*)   (ws + 75497472);
  float*  gwv  = (float*) (ws + 75530240);
  float*  projP = out;  // scratch: fully dead before gemm_fused writes out

  // 1) all independent prep in one saturating launch
  prep_kernel<<<5760, 256, 0, stream>>>(x, base_W, routerW, A, B, Rm,
                                        xb, WbT, BbT, PabT, gidx, gwv);
  // 2) proj split-K GEMM (non-atomic partials into d_out scratch)
  gemm_proj_kernel<<<dim3(32, 2, 4), 256, 0, stream>>>(xb, PabT, projP);
  // 3) gating -> C2 (sums 4 partials)
  gating_kernel<<<4096, 384, 0, stream>>>(projP, gidx, gwv, C2b);
  // 4) fused base+delta GEMM, 256^2 counted-vmcnt two-phase pipeline, single out write
  gemm_fused256<<<dim3(256), 512, 0, stream>>>(xb, WbT, C2b, BbT, out);
}

// Round 4
// 358.078 us; speedup vs baseline: 10.7997x; 1.0161x over previous
//
#include <hip/hip_runtime.h>
#include <hip/hip_bf16.h>
#include <math.h>

typedef __bf16 bf16_t;
typedef __bf16 bf16x4_t __attribute__((ext_vector_type(4)));
typedef __bf16 bf16x8_t __attribute__((ext_vector_type(8)));
typedef float  f32x4_t  __attribute__((ext_vector_type(4)));

#define N_TOK 4096
#define D_IN  4096
#define O_OUT 4096
#define NEXP  8
#define NHEAD 3
#define RANK  16
#define KC2   384      // E*H*R
#define PCOLS 256      // padded projection cols (152 used)
#define SCALING_F 2.0f

// ---------------- prep building blocks ----------------

// 64x64 transpose tile fp32 -> bf16, vectorized, <=2-way LDS aliasing (free).
__device__ __forceinline__ void transpose_tile(const float* __restrict__ src,
                                               bf16_t* __restrict__ dst,
                                               int Rr, int Cc, int r0, int c0,
                                               float (*tile)[65]) {
  int q  = threadIdx.x & 15;
  int r4 = threadIdx.x >> 4;
  #pragma unroll
  for (int g = 0; g < 4; ++g) {
    int r = r4 + g * 16;
    float4 v = *(const float4*)(src + (size_t)(r0 + r) * Cc + c0 + q * 4);
    tile[r][q * 4 + 0] = v.x; tile[r][q * 4 + 1] = v.y;
    tile[r][q * 4 + 2] = v.z; tile[r][q * 4 + 3] = v.w;
  }
  __syncthreads();
  #pragma unroll
  for (int g = 0; g < 4; ++g) {
    int c = r4 + g * 16;
    bf16x4_t o = { (bf16_t)tile[q * 4 + 0][c], (bf16_t)tile[q * 4 + 1][c],
                   (bf16_t)tile[q * 4 + 2][c], (bf16_t)tile[q * 4 + 3][c] };
    *(bf16x4_t*)(dst + (size_t)(c0 + c) * Rr + r0 + q * 4) = o;
  }
}

// ---------------- ONE prep kernel: all independent pre-GEMM work ----------------
__global__ __launch_bounds__(256) void prep_kernel(const float* __restrict__ x,
                                                   const float* __restrict__ base_W,
                                                   const float* __restrict__ rw,
                                                   const float* __restrict__ A,
                                                   const float* __restrict__ B,
                                                   const float* __restrict__ Rm,
                                                   bf16_t* __restrict__ xb,
                                                   bf16_t* __restrict__ WbT,
                                                   bf16_t* __restrict__ BbT,
                                                   bf16_t* __restrict__ PabT,
                                                   int* __restrict__ gidx,
                                                   float* __restrict__ gwv) {
  __shared__ float tile[64][65];
  int b = blockIdx.x;
  if (b < 4096) {
    transpose_tile(base_W, WbT, 4096, 4096, (b & 63) * 64, (b >> 6) * 64, tile);
  } else if (b < 5120) {
    int lane = threadIdx.x & 63;
    int wv = threadIdx.x >> 6;
    int n = (b - 4096) * 4 + wv;
    const float4* xv = (const float4*)(x + (size_t)n * D_IN);
    bf16x4_t* xo = (bf16x4_t*)(xb + (size_t)n * D_IN);
    float acc[NEXP] = {0, 0, 0, 0, 0, 0, 0, 0};
    for (int d = lane; d < D_IN / 4; d += 64) {
      float4 xx = xv[d];
      bf16x4_t ob = { (bf16_t)xx.x, (bf16_t)xx.y, (bf16_t)xx.z, (bf16_t)xx.w };
      xo[d] = ob;
      #pragma unroll
      for (int e = 0; e < NEXP; ++e) {
        float4 ww = ((const float4*)(rw + (size_t)e * D_IN))[d];
        acc[e] += xx.x * ww.x + xx.y * ww.y + xx.z * ww.z + xx.w * ww.w;
      }
    }
    #pragma unroll
    for (int e = 0; e < NEXP; ++e) {
      float v = acc[e];
      #pragma unroll
      for (int o = 32; o > 0; o >>= 1) v += __shfl_down(v, o);
      acc[e] = v;
    }
    if (lane == 0) {
      int i0 = 0; float l0 = acc[0];
      #pragma unroll
      for (int e = 1; e < NEXP; ++e) if (acc[e] > l0) { l0 = acc[e]; i0 = e; }
      int i1 = -1; float l1 = -3.4e38f;
      #pragma unroll
      for (int e = 0; e < NEXP; ++e) if (e != i0 && acc[e] > l1) { l1 = acc[e]; i1 = e; }
      float w0 = 1.f / (1.f + expf(l1 - l0));
      gidx[2 * n] = i0; gidx[2 * n + 1] = i1;
      gwv[2 * n] = w0;  gwv[2 * n + 1] = 1.f - w0;
    }
  } else if (b < 5504) {
    int t = b - 5120;
    transpose_tile(B, BbT, KC2, 4096, (t % 6) * 64, (t / 6) * 64, tile);
  } else {
    int c = b - 5504;  // 0..255: output row of PabT
    for (int d = threadIdx.x; d < D_IN; d += 256) {
      float v = 0.f;
      if (c < 128) {
        int e = c >> 4, r = c & 15;
        v = A[((size_t)e * D_IN + d) * RANK + r];
      } else if (c < 152) {
        int qq = c - 128; int e = qq / 3, h = qq - 3 * e;
        v = Rm[((size_t)e * D_IN + d) * NHEAD + h];
      }
      PabT[(size_t)c * D_IN + d] = (bf16_t)v;
    }
  }
}

// ---------------- gating: C2[n, e*48+h*16+r], summing 4 split-K partials ----------------
__global__ void gating_kernel(const float* __restrict__ projP, const int* __restrict__ gidx,
                              const float* __restrict__ gwv, bf16_t* __restrict__ C2b) {
  int n = blockIdx.x;
  int c = threadIdx.x;  // 0..383
  int e = c / 48;
  int h = (c % 48) / 16;
  int r = c & 15;
  int i0 = gidx[2 * n], i1 = gidx[2 * n + 1];
  float g = (e == i0) ? gwv[2 * n] : (e == i1) ? gwv[2 * n + 1] : 0.f;
  float val = 0.f;
  if (g != 0.f) {
    const float* p0 = projP + (size_t)n * PCOLS;
    const size_t S = (size_t)N_TOK * PCOLS;
    #define RD(cc) (p0[(cc)] + p0[(cc) + S] + p0[(cc) + 2 * S] + p0[(cc) + 3 * S])
    float h0 = RD(128 + e * 3 + 0);
    float h1 = RD(128 + e * 3 + 1);
    float h2 = RD(128 + e * 3 + 2);
    float av = RD(e * 16 + r);
    #undef RD
    float mx = fmaxf(h0, fmaxf(h1, h2));
    float e0 = expf(h0 - mx), e1 = expf(h1 - mx), e2 = expf(h2 - mx);
    float hw = (h == 0 ? e0 : h == 1 ? e1 : e2) / (e0 + e1 + e2);
    val = SCALING_F * g * hw * av;
  }
  C2b[(size_t)n * KC2 + c] = (bf16_t)val;
}

// ---------------- m97-style MFMA K-loop core (used by proj GEMM only) ----------------
__device__ __forceinline__ void run_kloop(f32x4_t (&acc)[4][4], bf16_t* sA, bf16_t* sB,
                                          const bf16_t* __restrict__ Ab, int lda,
                                          const bf16_t* __restrict__ Bb, int ldb, int K) {
  const int tid = threadIdx.x;
  const int lane = tid & 63;
  const int w = tid >> 6;
  const int wm = (w >> 1) * 64;
  const int wn = (w & 1) * 64;
  const int qd = lane >> 4;
  const int ln = lane & 15;
  const int sw = ln & 7;

  size_t offA[4], offB[4];
  int lo[4];
  #pragma unroll
  for (int t = 0; t < 4; ++t) {
    int c = tid + t * 256;
    int m = c >> 3, kc = (c & 7) ^ (m & 7);
    offA[t] = (size_t)m * lda + kc * 8;
    offB[t] = (size_t)m * ldb + kc * 8;
    lo[t] = c * 8;
  }
  int rowA[4], rowB[4];
  #pragma unroll
  for (int i = 0; i < 4; ++i) {
    rowA[i] = (wm + i * 16 + ln) * 64;
    rowB[i] = (wn + i * 16 + ln) * 64;
  }

  for (int k0 = 0; k0 < K; k0 += 64) {
    __syncthreads();
    #pragma unroll
    for (int t = 0; t < 4; ++t)
      __builtin_amdgcn_global_load_lds(
          (const __attribute__((address_space(1))) void*)(Ab + k0 + offA[t]),
          (__attribute__((address_space(3))) void*)(sA + lo[t]), 16, 0, 0);
    #pragma unroll
    for (int t = 0; t < 4; ++t)
      __builtin_amdgcn_global_load_lds(
          (const __attribute__((address_space(1))) void*)(Bb + k0 + offB[t]),
          (__attribute__((address_space(3))) void*)(sB + lo[t]), 16, 0, 0);
    __syncthreads();
    #pragma unroll
    for (int s = 0; s < 2; ++s) {
      bf16x8_t af[4], bfr[4];
      int kx = ((s * 4 + qd) ^ sw) * 8;
      #pragma unroll
      for (int i = 0; i < 4; ++i) af[i]  = *(const bf16x8_t*)(sA + rowA[i] + kx);
      #pragma unroll
      for (int i = 0; i < 4; ++i) bfr[i] = *(const bf16x8_t*)(sB + rowB[i] + kx);
      #pragma unroll
      for (int i = 0; i < 4; ++i)
        #pragma unroll
        for (int j = 0; j < 4; ++j)
          acc[i][j] = __builtin_amdgcn_mfma_f32_16x16x32_bf16(af[i], bfr[j], acc[i][j], 0, 0, 0);
    }
  }
}

// proj split-K GEMM: projP[kz][4096,256] = xb @ PabT^T partial (K slice 1024), plain stores.
__global__ __launch_bounds__(256) void gemm_proj_kernel(const bf16_t* __restrict__ xb,
                                                        const bf16_t* __restrict__ PabT,
                                                        float* __restrict__ projP) {
  __shared__ bf16_t sA[128 * 64];
  __shared__ bf16_t sB[128 * 64];
  int bm = blockIdx.x, bn = blockIdx.y, kz = blockIdx.z;
  f32x4_t acc[4][4] = {};
  run_kloop(acc, sA, sB,
            xb + (size_t)bm * 128 * D_IN + kz * 1024, D_IN,
            PabT + (size_t)bn * 128 * D_IN + kz * 1024, D_IN, 1024);
  const int lane = threadIdx.x & 63, w = threadIdx.x >> 6;
  const int wm = (w >> 1) * 64, wn = (w & 1) * 64, qd = lane >> 4, ln = lane & 15;
  float* Cb = projP + (size_t)kz * N_TOK * PCOLS + (size_t)bm * 128 * PCOLS + bn * 128;
  #pragma unroll
  for (int i = 0; i < 4; ++i)
    #pragma unroll
    for (int j = 0; j < 4; ++j) {
      int col = wn + j * 16 + ln;
      #pragma unroll
      for (int rg = 0; rg < 4; ++rg) {
        int row = wm + i * 16 + qd * 4 + rg;
        Cb[(size_t)row * PCOLS + col] = acc[i][j][rg];
      }
    }
}

// ---------------- fused big GEMM, 256x256 tile, BK=32, ring-4 counted-vmcnt pipeline ----
// Round-4 changes vs round-3 (barrier/vmcnt structure UNCHANGED, correctness-proven):
//  - no sched_barrier pinning except ONE pre-end-barrier pin (keeps slot-sc ds_reads from
//    sinking past the barrier into the next tile's stage-overwrite window)
//  - no explicit lgkmcnt(0): reads are plain loads -> compiler emits COUNTED lgkmcnt and
//    can overlap mfma16<0> with the a1 reads (m141 lesson: pinning defeats the scheduler)
//  - main loop unrolled x4 with compile-time ring-slot constants (no runtime slot VALU)
//  - per-thread global staging offsets (row*ld) hoisted out of the loop

__device__ __forceinline__ void stage2(const bf16_t* __restrict__ G, int k0,
                                       bf16_t* lbase, size_t g0, size_t g1, int tid) {
  __builtin_amdgcn_global_load_lds(
      (const __attribute__((address_space(1))) void*)(G + g0 + k0),
      (__attribute__((address_space(3))) void*)(lbase + tid * 8), 16, 0, 0);
  __builtin_amdgcn_global_load_lds(
      (const __attribute__((address_space(1))) void*)(G + g1 + k0),
      (__attribute__((address_space(3))) void*)(lbase + 4096 + tid * 8), 16, 0, 0);
}

// one 16-MFMA quadrant cluster, acc rows MB..MB+3
template <int MB>
__device__ __forceinline__ void mfma16(f32x4_t (&acc)[8][4], const bf16x8_t (&af)[4],
                                       const bf16x8_t (&bv)[4]) {
  __builtin_amdgcn_s_setprio(1);
  #pragma unroll
  for (int mi = 0; mi < 4; ++mi)
    #pragma unroll
    for (int nj = 0; nj < 4; ++nj)
      acc[MB + mi][nj] =
          __builtin_amdgcn_mfma_f32_16x16x32_bf16(af[mi], bv[nj], acc[MB + mi][nj], 0, 0, 0);
  __builtin_amdgcn_s_setprio(0);
}

// monolithic compute for tail iterations
__device__ __forceinline__ void compute256(f32x4_t (&acc)[8][4],
                                           const bf16_t* pA, const bf16_t* pB) {
  bf16x8_t af[8], bv[4];
  #pragma unroll
  for (int nj = 0; nj < 4; ++nj) bv[nj] = *(const bf16x8_t*)(pB + nj * 512);
  #pragma unroll
  for (int mi = 0; mi < 8; ++mi) af[mi] = *(const bf16x8_t*)(pA + mi * 512);
  __builtin_amdgcn_s_setprio(1);
  #pragma unroll
  for (int mi = 0; mi < 8; ++mi)
    #pragma unroll
    for (int nj = 0; nj < 4; ++nj)
      acc[mi][nj] = __builtin_amdgcn_mfma_f32_16x16x32_bf16(af[mi], bv[nj], acc[mi][nj], 0, 0, 0);
  __builtin_amdgcn_s_setprio(0);
}

// Main-loop tile body, slots as template constants.
// Schedule (identical barrier/vmcnt structure to round 3):
//   stage A(t+3); vmcnt(10); bar1; reads bv+a0; stage B(t+3); 16 MFMA (compiler-counted
//   lgkmcnt); reads a1; mid-bar; 16 MFMA; sched_barrier; end-bar
template <int SC, int SS>
__device__ __forceinline__ void tbody(f32x4_t (&acc)[8][4], bf16_t* sring,
                                      const bf16_t* __restrict__ A,
                                      const bf16_t* __restrict__ B, int k3,
                                      size_t gA0, size_t gA1, size_t gB0, size_t gB1,
                                      int aoff, int boff, int tid) {
  stage2(A, k3, sring + SS * 16384, gA0, gA1, tid);
  asm volatile("s_waitcnt vmcnt(10)" ::: "memory");    // tile t fully landed (per wave)
  __builtin_amdgcn_s_barrier();                        // all waves' tile-t LDS visible
  const bf16_t* pA = sring + SC * 16384 + aoff;
  const bf16_t* pB = sring + SC * 16384 + 8192 + boff;
  bf16x8_t bv[4], a0[4], a1[4];
  #pragma unroll
  for (int nj = 0; nj < 4; ++nj) bv[nj] = *(const bf16x8_t*)(pB + nj * 512);
  #pragma unroll
  for (int mi = 0; mi < 4; ++mi) a0[mi] = *(const bf16x8_t*)(pA + mi * 512);
  stage2(B, k3, sring + SS * 16384 + 8192, gB0, gB1, tid);
  mfma16<0>(acc, a0, bv);
  #pragma unroll
  for (int mi = 0; mi < 4; ++mi) a1[mi] = *(const bf16x8_t*)(pA + (4 + mi) * 512);
  __builtin_amdgcn_s_barrier();                        // mid barrier: role split
  mfma16<4>(acc, a1, bv);
  __builtin_amdgcn_sched_barrier(0);                   // pin slot-SC reads above end-bar
  __builtin_amdgcn_s_barrier();                        // slot SC reads done -> re-stageable
}

// runtime-slot variant for the (T-3)%4 leftover iteration
__device__ __forceinline__ void tbody_rt(f32x4_t (&acc)[8][4], bf16_t* sring,
                                         const bf16_t* __restrict__ A,
                                         const bf16_t* __restrict__ B, int k3,
                                         int sc, int ss,
                                         size_t gA0, size_t gA1, size_t gB0, size_t gB1,
                                         int aoff, int boff, int tid) {
  stage2(A, k3, sring + ss * 16384, gA0, gA1, tid);
  asm volatile("s_waitcnt vmcnt(10)" ::: "memory");
  __builtin_amdgcn_s_barrier();
  const bf16_t* pA = sring + sc * 16384 + aoff;
  const bf16_t* pB = sring + sc * 16384 + 8192 + boff;
  bf16x8_t bv[4], a0[4], a1[4];
  #pragma unroll
  for (int nj = 0; nj < 4; ++nj) bv[nj] = *(const bf16x8_t*)(pB + nj * 512);
  #pragma unroll
  for (int mi = 0; mi < 4; ++mi) a0[mi] = *(const bf16x8_t*)(pA + mi * 512);
  stage2(B, k3, sring + ss * 16384 + 8192, gB0, gB1, tid);
  mfma16<0>(acc, a0, bv);
  #pragma unroll
  for (int mi = 0; mi < 4; ++mi) a1[mi] = *(const bf16x8_t*)(pA + (4 + mi) * 512);
  __builtin_amdgcn_s_barrier();
  mfma16<4>(acc, a1, bv);
  __builtin_amdgcn_sched_barrier(0);
  __builtin_amdgcn_s_barrier();
}

__device__ __forceinline__ void kloop256(f32x4_t (&acc)[8][4], bf16_t* sring,
                                         const bf16_t* __restrict__ A, int lda,
                                         const bf16_t* __restrict__ B, int ldb,
                                         int K, int tid, int aoff, int boff) {
  // per-thread staging source offsets (16B slot: row = s>>2, chunk' = s&3,
  // inverse-swizzled source chunk per rule 21) -- loop-invariant, hoisted
  const int s0 = tid,       r0 = s0 >> 2, c0 = (s0 & 3) ^ ((r0 >> 1) & 3);
  const int s1 = 512 + tid, r1 = s1 >> 2, c1 = (s1 & 3) ^ ((r1 >> 1) & 3);
  const size_t gA0 = (size_t)r0 * lda + c0 * 8, gA1 = (size_t)r1 * lda + c1 * 8;
  const size_t gB0 = (size_t)r0 * ldb + c0 * 8, gB1 = (size_t)r1 * ldb + c1 * 8;

  const int T = K / 32;                   // 128 and 12 at the two call sites
  #pragma unroll
  for (int t = 0; t < 3; ++t) {           // prologue: tiles 0..2 -> slots 0..2 (12 glds)
    stage2(A, t * 32, sring + t * 16384, gA0, gA1, tid);
    stage2(B, t * 32, sring + t * 16384 + 8192, gB0, gB1, tid);
  }
  const int TM = T - 3;
  const int T4 = TM & ~3;
  int t = 0;
  for (; t < T4; t += 4) {                // x4 unroll: compile-time ring slots
    tbody<0, 3>(acc, sring, A, B, (t + 3) * 32, gA0, gA1, gB0, gB1, aoff, boff, tid);
    tbody<1, 0>(acc, sring, A, B, (t + 4) * 32, gA0, gA1, gB0, gB1, aoff, boff, tid);
    tbody<2, 1>(acc, sring, A, B, (t + 5) * 32, gA0, gA1, gB0, gB1, aoff, boff, tid);
    tbody<3, 2>(acc, sring, A, B, (t + 6) * 32, gA0, gA1, gB0, gB1, aoff, boff, tid);
  }
  for (; t < TM; ++t)                     // leftover (runtime slots)
    tbody_rt(acc, sring, A, B, (t + 3) * 32, t & 3, (t + 3) & 3,
             gA0, gA1, gB0, gB1, aoff, boff, tid);
  #pragma unroll 1
  for (; t < T; ++t) {                    // tail: drain 8 -> 4 -> 0
    const int rem = T - t;
    if (rem == 3)      asm volatile("s_waitcnt vmcnt(8)" ::: "memory");
    else if (rem == 2) asm volatile("s_waitcnt vmcnt(4)" ::: "memory");
    else               asm volatile("s_waitcnt vmcnt(0)" ::: "memory");
    __builtin_amdgcn_s_barrier();
    compute256(acc, sring + (t & 3) * 16384 + aoff, sring + (t & 3) * 16384 + 8192 + boff);
    __builtin_amdgcn_sched_barrier(0);
    __builtin_amdgcn_s_barrier();
  }
}

// 512 threads = 8 waves (2 M-groups x 4 N-groups); per-wave output 128x64.
// LDS: 4-slot ring x (A 16KB + B 16KB) = 128 KiB -> occupancy LDS-bound at 1 block/CU.
__global__ __launch_bounds__(512, 1) void gemm_fused256(const bf16_t* __restrict__ xb,
                                                        const bf16_t* __restrict__ WbT,
                                                        const bf16_t* __restrict__ C2b,
                                                        const bf16_t* __restrict__ BbT,
                                                        float* __restrict__ out) {
  __shared__ __align__(16) bf16_t sring[4 * 16384];  // [slot][A 8192 | B 8192]
  const int tid = threadIdx.x;
  const int lane = tid & 63;
  const int w = tid >> 6;
  const int wm = w >> 2;          // 0..1
  const int wn = w & 3;           // 0..3
  const int qd = lane >> 4;       // k-chunk
  const int ln = lane & 15;       // row-in-frag
  const int swz8 = ((qd ^ ((ln >> 1) & 3)) << 3);  // swizzled k-chunk, elem units

  // XCD-aware bijective swizzle (256 blocks, 256 % 8 == 0)
  int b = blockIdx.x;
  int sw = (b & 7) * 32 + (b >> 3);
  int bm = sw >> 4, bn = sw & 15;

  const int aoff = (wm * 128 + ln) * 32 + swz8;
  const int boff = (wn * 64 + ln) * 32 + swz8;

  f32x4_t acc[8][4] = {};

  kloop256(acc, sring, xb  + (size_t)bm * 256 * D_IN, D_IN,
                       WbT + (size_t)bn * 256 * D_IN, D_IN, D_IN, tid, aoff, boff);
  kloop256(acc, sring, C2b + (size_t)bm * 256 * KC2,  KC2,
                       BbT + (size_t)bn * 256 * KC2,  KC2,  KC2,  tid, aoff, boff);

  float* Cb = out + (size_t)(bm * 256 + wm * 128) * O_OUT + bn * 256 + wn * 64;
  #pragma unroll
  for (int mi = 0; mi < 8; ++mi)
    #pragma unroll
    for (int nj = 0; nj < 4; ++nj)
      #pragma unroll
      for (int rg = 0; rg < 4; ++rg)
        Cb[(size_t)(mi * 16 + qd * 4 + rg) * O_OUT + nj * 16 + ln] = acc[mi][nj][rg];
}

// ---------------- launch ----------------
// ws layout (bytes):
//   xb    @ 0         : 33554432  (bf16 [4096,4096])
//   WbT   @ 33554432  : 33554432  (bf16 [4096,4096])
//   PabT  @ 67108864  : 2097152   (bf16 [256,4096])
//   BbT   @ 69206016  : 3145728   (bf16 [4096,384])
//   C2b   @ 72351744  : 3145728   (bf16 [4096,384])
//   gidx  @ 75497472  : 32768
//   gwv   @ 75530240  : 32768
// projP [4][4096][256] fp32 (16 MB) lives in d_out (dead until final GEMM overwrites).
extern "C" void kernel_launch(void* const* d_in, const int* in_sizes, int n_in,
                              void* d_out, int out_size, void* d_ws, size_t ws_size,
                              hipStream_t stream) {
  const float* x       = (const float*)d_in[0];
  const float* base_W  = (const float*)d_in[1];
  const float* routerW = (const float*)d_in[2];
  const float* A       = (const float*)d_in[3];
  const float* B       = (const float*)d_in[4];
  const float* Rm      = (const float*)d_in[5];
  float* out = (float*)d_out;
  char* ws = (char*)d_ws;

  bf16_t* xb   = (bf16_t*)(ws);
  bf16_t* WbT  = (bf16_t*)(ws + 33554432);
  bf16_t* PabT = (bf16_t*)(ws + 67108864);
  bf16_t* BbT  = (bf16_t*)(ws + 69206016);
  bf16_t* C2b  = (bf16_t*)(ws + 72351744);
  int*    gidx = (int*)   (ws + 75497472);
  float*  gwv  = (float*) (ws + 75530240);
  float*  projP = out;  // scratch: fully dead before gemm_fused writes out

  // 1) all independent prep in one saturating launch
  prep_kernel<<<5760, 256, 0, stream>>>(x, base_W, routerW, A, B, Rm,
                                        xb, WbT, BbT, PabT, gidx, gwv);
  // 2) proj split-K GEMM (non-atomic partials into d_out scratch)
  gemm_proj_kernel<<<dim3(32, 2, 4), 256, 0, stream>>>(xb, PabT, projP);
  // 3) gating -> C2 (sums 4 partials)
  gating_kernel<<<4096, 384, 0, stream>>>(projP, gidx, gwv, C2b);
  // 4) fused base+delta GEMM, 256^2 counted-vmcnt two-phase pipeline, single out write
  gemm_fused256<<<dim3(256), 512, 0, stream>>>(xb, WbT, C2b, BbT, out);
}

// Round 5
// 356.167 us; speedup vs baseline: 10.8577x; 1.0054x over previous
//
#include <hip/hip_runtime.h>
#include <hip/hip_bf16.h>
#include <math.h>

typedef __bf16 bf16_t;
typedef __bf16 bf16x4_t __attribute__((ext_vector_type(4)));
typedef __bf16 bf16x8_t __attribute__((ext_vector_type(8)));
typedef float  f32x4_t  __attribute__((ext_vector_type(4)));

#define N_TOK 4096
#define D_IN  4096
#define O_OUT 4096
#define NEXP  8
#define NHEAD 3
#define RANK  16
#define KC2   384      // E*H*R
#define PCOLS 256      // padded projection cols (152 used)
#define NKZ   8        // proj split-K factor
#define SCALING_F 2.0f

// ---------------- prep building blocks ----------------

// 64x64 transpose tile fp32 -> bf16. Read stage unchanged (proven); write stage now
// emits 16B bf16x8 stores (2/thread) instead of 4x8B. LDS reads (8j+cc+i) mod 32:
// exactly 2-way aliasing = free (m136).
__device__ __forceinline__ void transpose_tile(const float* __restrict__ src,
                                               bf16_t* __restrict__ dst,
                                               int Rr, int Cc, int r0, int c0,
                                               float (*tile)[65]) {
  int q  = threadIdx.x & 15;
  int r4 = threadIdx.x >> 4;
  #pragma unroll
  for (int g = 0; g < 4; ++g) {
    int r = r4 + g * 16;
    float4 v = *(const float4*)(src + (size_t)(r0 + r) * Cc + c0 + q * 4);
    tile[r][q * 4 + 0] = v.x; tile[r][q * 4 + 1] = v.y;
    tile[r][q * 4 + 2] = v.z; tile[r][q * 4 + 3] = v.w;
  }
  __syncthreads();
  int j  = threadIdx.x & 7;   // out col-chunk (8 src rows)
  int cc = threadIdx.x >> 3;  // out row 0..31 (+32)
  #pragma unroll
  for (int h = 0; h < 2; ++h) {
    int c = cc + h * 32;
    bf16x8_t o;
    #pragma unroll
    for (int i = 0; i < 8; ++i) o[i] = (bf16_t)tile[j * 8 + i][c];
    *(bf16x8_t*)(dst + (size_t)(c0 + c) * Rr + r0 + j * 8) = o;
  }
}

// ---------------- ONE prep kernel: all independent pre-GEMM work ----------------
__global__ __launch_bounds__(256) void prep_kernel(const float* __restrict__ x,
                                                   const float* __restrict__ base_W,
                                                   const float* __restrict__ rw,
                                                   const float* __restrict__ A,
                                                   const float* __restrict__ B,
                                                   const float* __restrict__ Rm,
                                                   bf16_t* __restrict__ xb,
                                                   bf16_t* __restrict__ WbT,
                                                   bf16_t* __restrict__ BbT,
                                                   bf16_t* __restrict__ PabT,
                                                   int* __restrict__ gidx,
                                                   float* __restrict__ gwv) {
  __shared__ float tile[64][65];
  int b = blockIdx.x;
  if (b < 4096) {
    transpose_tile(base_W, WbT, 4096, 4096, (b & 63) * 64, (b >> 6) * 64, tile);
  } else if (b < 5120) {
    int lane = threadIdx.x & 63;
    int wv = threadIdx.x >> 6;
    int n = (b - 4096) * 4 + wv;
    const float4* xv = (const float4*)(x + (size_t)n * D_IN);
    bf16x4_t* xo = (bf16x4_t*)(xb + (size_t)n * D_IN);
    float acc[NEXP] = {0, 0, 0, 0, 0, 0, 0, 0};
    for (int d = lane; d < D_IN / 4; d += 64) {
      float4 xx = xv[d];
      bf16x4_t ob = { (bf16_t)xx.x, (bf16_t)xx.y, (bf16_t)xx.z, (bf16_t)xx.w };
      xo[d] = ob;
      #pragma unroll
      for (int e = 0; e < NEXP; ++e) {
        float4 ww = ((const float4*)(rw + (size_t)e * D_IN))[d];
        acc[e] += xx.x * ww.x + xx.y * ww.y + xx.z * ww.z + xx.w * ww.w;
      }
    }
    #pragma unroll
    for (int e = 0; e < NEXP; ++e) {
      float v = acc[e];
      #pragma unroll
      for (int o = 32; o > 0; o >>= 1) v += __shfl_down(v, o);
      acc[e] = v;
    }
    if (lane == 0) {
      int i0 = 0; float l0 = acc[0];
      #pragma unroll
      for (int e = 1; e < NEXP; ++e) if (acc[e] > l0) { l0 = acc[e]; i0 = e; }
      int i1 = -1; float l1 = -3.4e38f;
      #pragma unroll
      for (int e = 0; e < NEXP; ++e) if (e != i0 && acc[e] > l1) { l1 = acc[e]; i1 = e; }
      float w0 = 1.f / (1.f + expf(l1 - l0));
      gidx[2 * n] = i0; gidx[2 * n + 1] = i1;
      gwv[2 * n] = w0;  gwv[2 * n + 1] = 1.f - w0;
    }
  } else if (b < 5504) {
    int t = b - 5120;
    transpose_tile(B, BbT, KC2, 4096, (t % 6) * 64, (t / 6) * 64, tile);
  } else {
    int c = b - 5504;  // 0..255: output row of PabT
    for (int d = threadIdx.x; d < D_IN; d += 256) {
      float v = 0.f;
      if (c < 128) {
        int e = c >> 4, r = c & 15;
        v = A[((size_t)e * D_IN + d) * RANK + r];
      } else if (c < 152) {
        int qq = c - 128; int e = qq / 3, h = qq - 3 * e;
        v = Rm[((size_t)e * D_IN + d) * NHEAD + h];
      }
      PabT[(size_t)c * D_IN + d] = (bf16_t)v;
    }
  }
}

// ---------------- gating: C2[n, e*48+h*16+r], summing NKZ split-K partials ----------------
__global__ void gating_kernel(const float* __restrict__ projP, const int* __restrict__ gidx,
                              const float* __restrict__ gwv, bf16_t* __restrict__ C2b) {
  int n = blockIdx.x;
  int c = threadIdx.x;  // 0..383
  int e = c / 48;
  int h = (c % 48) / 16;
  int r = c & 15;
  int i0 = gidx[2 * n], i1 = gidx[2 * n + 1];
  float g = (e == i0) ? gwv[2 * n] : (e == i1) ? gwv[2 * n + 1] : 0.f;
  float val = 0.f;
  if (g != 0.f) {
    const float* p0 = projP + (size_t)n * PCOLS;
    const size_t S = (size_t)N_TOK * PCOLS;
    float h0 = 0.f, h1 = 0.f, h2 = 0.f, av = 0.f;
    #pragma unroll
    for (int z = 0; z < NKZ; ++z) {
      const float* pz = p0 + (size_t)z * S;
      h0 += pz[128 + e * 3 + 0];
      h1 += pz[128 + e * 3 + 1];
      h2 += pz[128 + e * 3 + 2];
      av += pz[e * 16 + r];
    }
    float mx = fmaxf(h0, fmaxf(h1, h2));
    float e0 = expf(h0 - mx), e1 = expf(h1 - mx), e2 = expf(h2 - mx);
    float hw = (h == 0 ? e0 : h == 1 ? e1 : e2) / (e0 + e1 + e2);
    val = SCALING_F * g * hw * av;
  }
  C2b[(size_t)n * KC2 + c] = (bf16_t)val;
}

// ---------------- m97-style MFMA K-loop core (used by proj GEMM only) ----------------
__device__ __forceinline__ void run_kloop(f32x4_t (&acc)[4][4], bf16_t* sA, bf16_t* sB,
                                          const bf16_t* __restrict__ Ab, int lda,
                                          const bf16_t* __restrict__ Bb, int ldb, int K) {
  const int tid = threadIdx.x;
  const int lane = tid & 63;
  const int w = tid >> 6;
  const int wm = (w >> 1) * 64;
  const int wn = (w & 1) * 64;
  const int qd = lane >> 4;
  const int ln = lane & 15;
  const int sw = ln & 7;

  size_t offA[4], offB[4];
  int lo[4];
  #pragma unroll
  for (int t = 0; t < 4; ++t) {
    int c = tid + t * 256;
    int m = c >> 3, kc = (c & 7) ^ (m & 7);
    offA[t] = (size_t)m * lda + kc * 8;
    offB[t] = (size_t)m * ldb + kc * 8;
    lo[t] = c * 8;
  }
  int rowA[4], rowB[4];
  #pragma unroll
  for (int i = 0; i < 4; ++i) {
    rowA[i] = (wm + i * 16 + ln) * 64;
    rowB[i] = (wn + i * 16 + ln) * 64;
  }

  for (int k0 = 0; k0 < K; k0 += 64) {
    __syncthreads();
    #pragma unroll
    for (int t = 0; t < 4; ++t)
      __builtin_amdgcn_global_load_lds(
          (const __attribute__((address_space(1))) void*)(Ab + k0 + offA[t]),
          (__attribute__((address_space(3))) void*)(sA + lo[t]), 16, 0, 0);
    #pragma unroll
    for (int t = 0; t < 4; ++t)
      __builtin_amdgcn_global_load_lds(
          (const __attribute__((address_space(1))) void*)(Bb + k0 + offB[t]),
          (__attribute__((address_space(3))) void*)(sB + lo[t]), 16, 0, 0);
    __syncthreads();
    #pragma unroll
    for (int s = 0; s < 2; ++s) {
      bf16x8_t af[4], bfr[4];
      int kx = ((s * 4 + qd) ^ sw) * 8;
      #pragma unroll
      for (int i = 0; i < 4; ++i) af[i]  = *(const bf16x8_t*)(sA + rowA[i] + kx);
      #pragma unroll
      for (int i = 0; i < 4; ++i) bfr[i] = *(const bf16x8_t*)(sB + rowB[i] + kx);
      #pragma unroll
      for (int i = 0; i < 4; ++i)
        #pragma unroll
        for (int j = 0; j < 4; ++j)
          acc[i][j] = __builtin_amdgcn_mfma_f32_16x16x32_bf16(af[i], bfr[j], acc[i][j], 0, 0, 0);
    }
  }
}

// proj split-K GEMM: projP[kz][4096,256] = xb @ PabT^T partial (K slice 512).
// NKZ=8 -> 512 blocks = 2 blocks/CU: inter-block overlap hides the m97 loop latency.
__global__ __launch_bounds__(256) void gemm_proj_kernel(const bf16_t* __restrict__ xb,
                                                        const bf16_t* __restrict__ PabT,
                                                        float* __restrict__ projP) {
  __shared__ bf16_t sA[128 * 64];
  __shared__ bf16_t sB[128 * 64];
  int bm = blockIdx.x, bn = blockIdx.y, kz = blockIdx.z;
  f32x4_t acc[4][4] = {};
  run_kloop(acc, sA, sB,
            xb + (size_t)bm * 128 * D_IN + kz * 512, D_IN,
            PabT + (size_t)bn * 128 * D_IN + kz * 512, D_IN, 512);
  const int lane = threadIdx.x & 63, w = threadIdx.x >> 6;
  const int wm = (w >> 1) * 64, wn = (w & 1) * 64, qd = lane >> 4, ln = lane & 15;
  float* Cb = projP + (size_t)kz * N_TOK * PCOLS + (size_t)bm * 128 * PCOLS + bn * 128;
  #pragma unroll
  for (int i = 0; i < 4; ++i)
    #pragma unroll
    for (int j = 0; j < 4; ++j) {
      int col = wn + j * 16 + ln;
      #pragma unroll
      for (int rg = 0; rg < 4; ++rg) {
        int row = wm + i * 16 + qd * 4 + rg;
        Cb[(size_t)row * PCOLS + col] = acc[i][j][rg];
      }
    }
}

// ---------------- fused big GEMM, 256x256 tile, BK=64, ring-2 counted-vmcnt pipeline ----
// Round-5: BK 32->64 (m201 recipe). Same 128 KiB LDS as ring-4/BK=32, but 64 MFMA per
// 3-barrier tile instead of 32 -> per-MFMA barrier/wait overhead halved.
// LDS layout per slot: A[256 rows][64 k] + B[256][64], row = 128B, chunk c in [0,8) of
// 16B; swizzle c' = c ^ (row&7) spreads a fragment-read's 64 lanes evenly over the 8
// bank-quads (balanced 8 lanes/quad = conflict-free; verified 0 conflicts on the BK=32
// analog). Stage: linear LDS dest + inverse-swizzled global source (rule 21).
// vmcnt: steady state stage-A(t+1) -> 12 outstanding -> vmcnt(4) drains tile t exactly,
// keeps t+1's A in flight; stage-B(t+1) issues inside sub-step 0; tail vmcnt(0).

#define SLOT 32768  // bf16 elems per ring slot (A 16384 | B 16384)

__device__ __forceinline__ void stage4(const bf16_t* __restrict__ G, int k0,
                                       bf16_t* lbase, const size_t (&g)[4], int tid) {
  #pragma unroll
  for (int i = 0; i < 4; ++i)
    __builtin_amdgcn_global_load_lds(
        (const __attribute__((address_space(1))) void*)(G + g[i] + k0),
        (__attribute__((address_space(3))) void*)(lbase + (i * 512 + tid) * 8), 16, 0, 0);
}

// one 16-MFMA quadrant cluster, acc rows MB..MB+3
template <int MB>
__device__ __forceinline__ void mfma16(f32x4_t (&acc)[8][4], const bf16x8_t (&af)[4],
                                       const bf16x8_t (&bv)[4]) {
  __builtin_amdgcn_s_setprio(1);
  #pragma unroll
  for (int mi = 0; mi < 4; ++mi)
    #pragma unroll
    for (int nj = 0; nj < 4; ++nj)
      acc[MB + mi][nj] =
          __builtin_amdgcn_mfma_f32_16x16x32_bf16(af[mi], bv[nj], acc[MB + mi][nj], 0, 0, 0);
  __builtin_amdgcn_s_setprio(0);
}

// one k-sub-step (k-chunk kx): 12 ds_reads + 32 MFMA, two-phase a0/a1
__device__ __forceinline__ void substep64(f32x4_t (&acc)[8][4], const bf16_t* pA,
                                          const bf16_t* pB, int kx) {
  bf16x8_t bv[4], a0[4], a1[4];
  #pragma unroll
  for (int nj = 0; nj < 4; ++nj) bv[nj] = *(const bf16x8_t*)(pB + nj * 1024 + kx);
  #pragma unroll
  for (int mi = 0; mi < 4; ++mi) a0[mi] = *(const bf16x8_t*)(pA + mi * 1024 + kx);
  mfma16<0>(acc, a0, bv);
  #pragma unroll
  for (int mi = 0; mi < 4; ++mi) a1[mi] = *(const bf16x8_t*)(pA + (4 + mi) * 1024 + kx);
  mfma16<4>(acc, a1, bv);
}

// main-loop tile body: compute slot SC, stage tile(t+1) into slot SC^1
template <int SC>
__device__ __forceinline__ void tbody64(f32x4_t (&acc)[8][4], bf16_t* sring,
                                        const bf16_t* __restrict__ A,
                                        const bf16_t* __restrict__ B, int k1,
                                        const size_t (&gA)[4], const size_t (&gB)[4],
                                        int aoff, int boff, int kx0, int kx1, int tid) {
  stage4(A, k1, sring + (SC ^ 1) * SLOT, gA, tid);
  asm volatile("s_waitcnt vmcnt(4)" ::: "memory");  // tile t fully landed (per wave)
  __builtin_amdgcn_s_barrier();                     // tile-t LDS visible to all waves
  const bf16_t* pA = sring + SC * SLOT + aoff;
  const bf16_t* pB = sring + SC * SLOT + 16384 + boff;
  // sub-step 0 with B-stage interleaved
  bf16x8_t bv[4], a0[4], a1[4];
  #pragma unroll
  for (int nj = 0; nj < 4; ++nj) bv[nj] = *(const bf16x8_t*)(pB + nj * 1024 + kx0);
  #pragma unroll
  for (int mi = 0; mi < 4; ++mi) a0[mi] = *(const bf16x8_t*)(pA + mi * 1024 + kx0);
  stage4(B, k1, sring + (SC ^ 1) * SLOT + 16384, gB, tid);
  mfma16<0>(acc, a0, bv);
  #pragma unroll
  for (int mi = 0; mi < 4; ++mi) a1[mi] = *(const bf16x8_t*)(pA + (4 + mi) * 1024 + kx0);
  mfma16<4>(acc, a1, bv);
  __builtin_amdgcn_s_barrier();                     // mid barrier: wave role split
  substep64(acc, pA, pB, kx1);
  __builtin_amdgcn_sched_barrier(0);                // pin slot-SC reads above end-bar
  __builtin_amdgcn_s_barrier();                     // slot SC reads done -> re-stageable
}

// tail tile (no prefetch): drain all loads, compute slot SC
__device__ __forceinline__ void tail64(f32x4_t (&acc)[8][4], const bf16_t* slotbase,
                                       int aoff, int boff, int kx0, int kx1) {
  asm volatile("s_waitcnt vmcnt(0)" ::: "memory");
  __builtin_amdgcn_s_barrier();
  const bf16_t* pA = slotbase + aoff;
  const bf16_t* pB = slotbase + 16384 + boff;
  substep64(acc, pA, pB, kx0);
  __builtin_amdgcn_s_barrier();
  substep64(acc, pA, pB, kx1);
  __builtin_amdgcn_sched_barrier(0);
  __builtin_amdgcn_s_barrier();
}

__device__ __forceinline__ void kloop64(f32x4_t (&acc)[8][4], bf16_t* sring,
                                        const bf16_t* __restrict__ A, int lda,
                                        const bf16_t* __restrict__ B, int ldb,
                                        int K, int tid, int aoff, int boff,
                                        int kx0, int kx1) {
  // per-thread staging source offsets: 16B unit s -> row = s>>3, stored chunk c' = s&7,
  // source chunk = c' ^ (row&7) (inverse swizzle; same involution as the ds_read side)
  size_t gA[4], gB[4];
  #pragma unroll
  for (int i = 0; i < 4; ++i) {
    int s = i * 512 + tid;
    int row = s >> 3;
    int c = (s & 7) ^ (row & 7);
    gA[i] = (size_t)row * lda + c * 8;
    gB[i] = (size_t)row * ldb + c * 8;
  }
  const int T = K / 64;                  // 64 and 6 at the two call sites (both even)
  stage4(A, 0, sring, gA, tid);          // prologue: tile 0 -> slot 0
  stage4(B, 0, sring + 16384, gB, tid);
  int t = 0;
  for (; t + 1 < T - 1; t += 2) {        // x2 unroll, compile-time slots
    tbody64<0>(acc, sring, A, B, (t + 1) * 64, gA, gB, aoff, boff, kx0, kx1, tid);
    tbody64<1>(acc, sring, A, B, (t + 2) * 64, gA, gB, aoff, boff, kx0, kx1, tid);
  }
  for (; t < T - 1; ++t) {               // leftover (T-1 odd -> exactly one, even t)
    if (t & 1) tbody64<1>(acc, sring, A, B, (t + 1) * 64, gA, gB, aoff, boff, kx0, kx1, tid);
    else       tbody64<0>(acc, sring, A, B, (t + 1) * 64, gA, gB, aoff, boff, kx0, kx1, tid);
  }
  tail64(acc, sring + ((T - 1) & 1) * SLOT, aoff, boff, kx0, kx1);
}

// 512 threads = 8 waves (2 M-groups x 4 N-groups); per-wave output 128x64.
// LDS: 2-slot ring x (A 32KB + B 32KB) = 128 KiB -> 1 block/CU, 2 waves/SIMD (8-wave
// block forces <=256 VGPR).
__global__ __launch_bounds__(512, 1) void gemm_fused256(const bf16_t* __restrict__ xb,
                                                        const bf16_t* __restrict__ WbT,
                                                        const bf16_t* __restrict__ C2b,
                                                        const bf16_t* __restrict__ BbT,
                                                        float* __restrict__ out) {
  __shared__ __align__(16) bf16_t sring[2 * SLOT];
  const int tid = threadIdx.x;
  const int lane = tid & 63;
  const int w = tid >> 6;
  const int wm = w >> 2;          // 0..1
  const int wn = w & 3;           // 0..3
  const int qd = lane >> 4;       // k-chunk within sub-step
  const int ln = lane & 15;       // row-in-frag

  // XCD-aware bijective swizzle (256 blocks, 256 % 8 == 0)
  int b = blockIdx.x;
  int sw = (b & 7) * 32 + (b >> 3);
  int bm = sw >> 4, bn = sw & 15;

  // fragment LDS offsets (elems): row*64 within a 256x64 matrix; swizzled k-chunk
  const int aoff = (wm * 128 + ln) * 64;
  const int boff = (wn * 64 + ln) * 64;
  const int kx0 = ((qd) ^ (ln & 7)) * 8;       // sub-step 0 chunk (row&7 == ln&7)
  const int kx1 = ((4 + qd) ^ (ln & 7)) * 8;   // sub-step 1 chunk

  f32x4_t acc[8][4] = {};

  kloop64(acc, sring, xb  + (size_t)bm * 256 * D_IN, D_IN,
                      WbT + (size_t)bn * 256 * D_IN, D_IN, D_IN, tid, aoff, boff, kx0, kx1);
  kloop64(acc, sring, C2b + (size_t)bm * 256 * KC2,  KC2,
                      BbT + (size_t)bn * 256 * KC2,  KC2,  KC2,  tid, aoff, boff, kx0, kx1);

  float* Cb = out + (size_t)(bm * 256 + wm * 128) * O_OUT + bn * 256 + wn * 64;
  #pragma unroll
  for (int mi = 0; mi < 8; ++mi)
    #pragma unroll
    for (int nj = 0; nj < 4; ++nj)
      #pragma unroll
      for (int rg = 0; rg < 4; ++rg)
        Cb[(size_t)(mi * 16 + qd * 4 + rg) * O_OUT + nj * 16 + ln] = acc[mi][nj][rg];
}

// ---------------- launch ----------------
// ws layout (bytes):
//   xb    @ 0         : 33554432  (bf16 [4096,4096])
//   WbT   @ 33554432  : 33554432  (bf16 [4096,4096])
//   PabT  @ 67108864  : 2097152   (bf16 [256,4096])
//   BbT   @ 69206016  : 3145728   (bf16 [4096,384])
//   C2b   @ 72351744  : 3145728   (bf16 [4096,384])
//   gidx  @ 75497472  : 32768
//   gwv   @ 75530240  : 32768
// projP [8][4096][256] fp32 (32 MB) lives in d_out (dead until final GEMM overwrites).
extern "C" void kernel_launch(void* const* d_in, const int* in_sizes, int n_in,
                              void* d_out, int out_size, void* d_ws, size_t ws_size,
                              hipStream_t stream) {
  const float* x       = (const float*)d_in[0];
  const float* base_W  = (const float*)d_in[1];
  const float* routerW = (const float*)d_in[2];
  const float* A       = (const float*)d_in[3];
  const float* B       = (const float*)d_in[4];
  const float* Rm      = (const float*)d_in[5];
  float* out = (float*)d_out;
  char* ws = (char*)d_ws;

  bf16_t* xb   = (bf16_t*)(ws);
  bf16_t* WbT  = (bf16_t*)(ws + 33554432);
  bf16_t* PabT = (bf16_t*)(ws + 67108864);
  bf16_t* BbT  = (bf16_t*)(ws + 69206016);
  bf16_t* C2b  = (bf16_t*)(ws + 72351744);
  int*    gidx = (int*)   (ws + 75497472);
  float*  gwv  = (float*) (ws + 75530240);
  float*  projP = out;  // scratch: fully dead before gemm_fused writes out

  // 1) all independent prep in one saturating launch
  prep_kernel<<<5760, 256, 0, stream>>>(x, base_W, routerW, A, B, Rm,
                                        xb, WbT, BbT, PabT, gidx, gwv);
  // 2) proj split-K GEMM (non-atomic partials into d_out scratch), 2 blocks/CU
  gemm_proj_kernel<<<dim3(32, 2, NKZ), 256, 0, stream>>>(xb, PabT, projP);
  // 3) gating -> C2 (sums NKZ partials)
  gating_kernel<<<4096, 384, 0, stream>>>(projP, gidx, gwv, C2b);
  // 4) fused base+delta GEMM, BK=64 ring-2 counted-vmcnt pipeline, single out write
  gemm_fused256<<<dim3(256), 512, 0, stream>>>(xb, WbT, C2b, BbT, out);
}

// Round 6
// 349.220 us; speedup vs baseline: 11.0737x; 1.0199x over previous
//
#include <hip/hip_runtime.h>
#include <hip/hip_bf16.h>
#include <math.h>

typedef __bf16 bf16_t;
typedef __bf16 bf16x4_t __attribute__((ext_vector_type(4)));
typedef __bf16 bf16x8_t __attribute__((ext_vector_type(8)));
typedef float  f32x4_t  __attribute__((ext_vector_type(4)));

#define N_TOK 4096
#define D_IN  4096
#define O_OUT 4096
#define NEXP  8
#define NHEAD 3
#define RANK  16
#define KC2   384      // E*H*R
#define PCOLS 256      // padded projection cols (152 used)
#define NKZ   8        // proj split-K factor
#define SCALING_F 2.0f

// ---------------- prep building blocks ----------------

// 64x64 transpose tile fp32 -> bf16; 16B bf16x8 stores; LDS reads 2-way aliased (free).
__device__ __forceinline__ void transpose_tile(const float* __restrict__ src,
                                               bf16_t* __restrict__ dst,
                                               int Rr, int Cc, int r0, int c0,
                                               float (*tile)[65]) {
  int q  = threadIdx.x & 15;
  int r4 = threadIdx.x >> 4;
  #pragma unroll
  for (int g = 0; g < 4; ++g) {
    int r = r4 + g * 16;
    float4 v = *(const float4*)(src + (size_t)(r0 + r) * Cc + c0 + q * 4);
    tile[r][q * 4 + 0] = v.x; tile[r][q * 4 + 1] = v.y;
    tile[r][q * 4 + 2] = v.z; tile[r][q * 4 + 3] = v.w;
  }
  __syncthreads();
  int j  = threadIdx.x & 7;   // out col-chunk (8 src rows)
  int cc = threadIdx.x >> 3;  // out row 0..31 (+32)
  #pragma unroll
  for (int h = 0; h < 2; ++h) {
    int c = cc + h * 32;
    bf16x8_t o;
    #pragma unroll
    for (int i = 0; i < 8; ++i) o[i] = (bf16_t)tile[j * 8 + i][c];
    *(bf16x8_t*)(dst + (size_t)(c0 + c) * Rr + r0 + j * 8) = o;
  }
}

// ---------------- ONE prep kernel: all independent pre-GEMM work ----------------
__global__ __launch_bounds__(256) void prep_kernel(const float* __restrict__ x,
                                                   const float* __restrict__ base_W,
                                                   const float* __restrict__ rw,
                                                   const float* __restrict__ A,
                                                   const float* __restrict__ B,
                                                   const float* __restrict__ Rm,
                                                   bf16_t* __restrict__ xb,
                                                   bf16_t* __restrict__ WbT,
                                                   bf16_t* __restrict__ BbT,
                                                   bf16_t* __restrict__ PabT,
                                                   int* __restrict__ gidx,
                                                   float* __restrict__ gwv) {
  __shared__ float tile[64][65];
  int b = blockIdx.x;
  if (b < 4096) {
    transpose_tile(base_W, WbT, 4096, 4096, (b & 63) * 64, (b >> 6) * 64, tile);
  } else if (b < 5120) {
    int lane = threadIdx.x & 63;
    int wv = threadIdx.x >> 6;
    int n = (b - 4096) * 4 + wv;
    const float4* xv = (const float4*)(x + (size_t)n * D_IN);
    bf16x4_t* xo = (bf16x4_t*)(xb + (size_t)n * D_IN);
    float acc[NEXP] = {0, 0, 0, 0, 0, 0, 0, 0};
    for (int d = lane; d < D_IN / 4; d += 64) {
      float4 xx = xv[d];
      bf16x4_t ob = { (bf16_t)xx.x, (bf16_t)xx.y, (bf16_t)xx.z, (bf16_t)xx.w };
      xo[d] = ob;
      #pragma unroll
      for (int e = 0; e < NEXP; ++e) {
        float4 ww = ((const float4*)(rw + (size_t)e * D_IN))[d];
        acc[e] += xx.x * ww.x + xx.y * ww.y + xx.z * ww.z + xx.w * ww.w;
      }
    }
    #pragma unroll
    for (int e = 0; e < NEXP; ++e) {
      float v = acc[e];
      #pragma unroll
      for (int o = 32; o > 0; o >>= 1) v += __shfl_down(v, o);
      acc[e] = v;
    }
    if (lane == 0) {
      int i0 = 0; float l0 = acc[0];
      #pragma unroll
      for (int e = 1; e < NEXP; ++e) if (acc[e] > l0) { l0 = acc[e]; i0 = e; }
      int i1 = -1; float l1 = -3.4e38f;
      #pragma unroll
      for (int e = 0; e < NEXP; ++e) if (e != i0 && acc[e] > l1) { l1 = acc[e]; i1 = e; }
      float w0 = 1.f / (1.f + expf(l1 - l0));
      gidx[2 * n] = i0; gidx[2 * n + 1] = i1;
      gwv[2 * n] = w0;  gwv[2 * n + 1] = 1.f - w0;
    }
  } else if (b < 5504) {
    int t = b - 5120;
    transpose_tile(B, BbT, KC2, 4096, (t % 6) * 64, (t / 6) * 64, tile);
  } else {
    int c = b - 5504;  // 0..255: output row of PabT
    for (int d = threadIdx.x; d < D_IN; d += 256) {
      float v = 0.f;
      if (c < 128) {
        int e = c >> 4, r = c & 15;
        v = A[((size_t)e * D_IN + d) * RANK + r];
      } else if (c < 152) {
        int qq = c - 128; int e = qq / 3, h = qq - 3 * e;
        v = Rm[((size_t)e * D_IN + d) * NHEAD + h];
      }
      PabT[(size_t)c * D_IN + d] = (bf16_t)v;
    }
  }
}

// ---------------- gating: C2[n, e*48+h*16+r], summing NKZ split-K partials ----------------
__global__ void gating_kernel(const float* __restrict__ projP, const int* __restrict__ gidx,
                              const float* __restrict__ gwv, bf16_t* __restrict__ C2b) {
  int n = blockIdx.x;
  int c = threadIdx.x;  // 0..383
  int e = c / 48;
  int h = (c % 48) / 16;
  int r = c & 15;
  int i0 = gidx[2 * n], i1 = gidx[2 * n + 1];
  float g = (e == i0) ? gwv[2 * n] : (e == i1) ? gwv[2 * n + 1] : 0.f;
  float val = 0.f;
  if (g != 0.f) {
    const float* p0 = projP + (size_t)n * PCOLS;
    const size_t S = (size_t)N_TOK * PCOLS;
    float h0 = 0.f, h1 = 0.f, h2 = 0.f, av = 0.f;
    #pragma unroll
    for (int z = 0; z < NKZ; ++z) {
      const float* pz = p0 + (size_t)z * S;
      h0 += pz[128 + e * 3 + 0];
      h1 += pz[128 + e * 3 + 1];
      h2 += pz[128 + e * 3 + 2];
      av += pz[e * 16 + r];
    }
    float mx = fmaxf(h0, fmaxf(h1, h2));
    float e0 = expf(h0 - mx), e1 = expf(h1 - mx), e2 = expf(h2 - mx);
    float hw = (h == 0 ? e0 : h == 1 ? e1 : e2) / (e0 + e1 + e2);
    val = SCALING_F * g * hw * av;
  }
  C2b[(size_t)n * KC2 + c] = (bf16_t)val;
}

// ---------------- m97-style MFMA K-loop core (used by proj GEMM only) ----------------
__device__ __forceinline__ void run_kloop(f32x4_t (&acc)[4][4], bf16_t* sA, bf16_t* sB,
                                          const bf16_t* __restrict__ Ab, int lda,
                                          const bf16_t* __restrict__ Bb, int ldb, int K) {
  const int tid = threadIdx.x;
  const int lane = tid & 63;
  const int w = tid >> 6;
  const int wm = (w >> 1) * 64;
  const int wn = (w & 1) * 64;
  const int qd = lane >> 4;
  const int ln = lane & 15;
  const int sw = ln & 7;

  size_t offA[4], offB[4];
  int lo[4];
  #pragma unroll
  for (int t = 0; t < 4; ++t) {
    int c = tid + t * 256;
    int m = c >> 3, kc = (c & 7) ^ (m & 7);
    offA[t] = (size_t)m * lda + kc * 8;
    offB[t] = (size_t)m * ldb + kc * 8;
    lo[t] = c * 8;
  }
  int rowA[4], rowB[4];
  #pragma unroll
  for (int i = 0; i < 4; ++i) {
    rowA[i] = (wm + i * 16 + ln) * 64;
    rowB[i] = (wn + i * 16 + ln) * 64;
  }

  for (int k0 = 0; k0 < K; k0 += 64) {
    __syncthreads();
    #pragma unroll
    for (int t = 0; t < 4; ++t)
      __builtin_amdgcn_global_load_lds(
          (const __attribute__((address_space(1))) void*)(Ab + k0 + offA[t]),
          (__attribute__((address_space(3))) void*)(sA + lo[t]), 16, 0, 0);
    #pragma unroll
    for (int t = 0; t < 4; ++t)
      __builtin_amdgcn_global_load_lds(
          (const __attribute__((address_space(1))) void*)(Bb + k0 + offB[t]),
          (__attribute__((address_space(3))) void*)(sB + lo[t]), 16, 0, 0);
    __syncthreads();
    #pragma unroll
    for (int s = 0; s < 2; ++s) {
      bf16x8_t af[4], bfr[4];
      int kx = ((s * 4 + qd) ^ sw) * 8;
      #pragma unroll
      for (int i = 0; i < 4; ++i) af[i]  = *(const bf16x8_t*)(sA + rowA[i] + kx);
      #pragma unroll
      for (int i = 0; i < 4; ++i) bfr[i] = *(const bf16x8_t*)(sB + rowB[i] + kx);
      #pragma unroll
      for (int i = 0; i < 4; ++i)
        #pragma unroll
        for (int j = 0; j < 4; ++j)
          acc[i][j] = __builtin_amdgcn_mfma_f32_16x16x32_bf16(af[i], bfr[j], acc[i][j], 0, 0, 0);
    }
  }
}

// proj split-K GEMM: projP[kz][4096,256] = xb @ PabT^T partial (K slice 512), 2 blocks/CU.
__global__ __launch_bounds__(256) void gemm_proj_kernel(const bf16_t* __restrict__ xb,
                                                        const bf16_t* __restrict__ PabT,
                                                        float* __restrict__ projP) {
  __shared__ bf16_t sA[128 * 64];
  __shared__ bf16_t sB[128 * 64];
  int bm = blockIdx.x, bn = blockIdx.y, kz = blockIdx.z;
  f32x4_t acc[4][4] = {};
  run_kloop(acc, sA, sB,
            xb + (size_t)bm * 128 * D_IN + kz * 512, D_IN,
            PabT + (size_t)bn * 128 * D_IN + kz * 512, D_IN, 512);
  const int lane = threadIdx.x & 63, w = threadIdx.x >> 6;
  const int wm = (w >> 1) * 64, wn = (w & 1) * 64, qd = lane >> 4, ln = lane & 15;
  float* Cb = projP + (size_t)kz * N_TOK * PCOLS + (size_t)bm * 128 * PCOLS + bn * 128;
  #pragma unroll
  for (int i = 0; i < 4; ++i)
    #pragma unroll
    for (int j = 0; j < 4; ++j) {
      int col = wn + j * 16 + ln;
      #pragma unroll
      for (int rg = 0; rg < 4; ++rg) {
        int row = wm + i * 16 + qd * 4 + rg;
        Cb[(size_t)row * PCOLS + col] = acc[i][j][rg];
      }
    }
}

// ---------------- fused big GEMM: 256x256, BK=32, ring-4, PHASE-PIPELINED reads --------
// Round-6: R4's ring-4 skeleton (slots, stages, barriers) + m201's key mechanism: the
// ds_reads feeding each phase's MFMA are issued ONE PHASE EARLIER, so MFMA never waits
// LDS latency. Visibility moved one barrier earlier: vmcnt(8) before the MID barrier
// guarantees tile t+1 landed (ledger: after stage-B(t+3), outstanding = t+1,t+2,t+3 = 12;
// vmcnt(8) forces the oldest 4 = tile t+1's), so phase b may pre-read slot (t+1)&3.
// Schedule per tile t (slot SC=t&3):
//   [carried: bv(t),a0(t) read during t-1 phase b]
//   stage A(t+3);  phase a: 16 MFMA (bv,a0) ; read a1(t) ; stage B(t+3)
//   vmcnt(8) ; mid-bar  (tile t+1 visible)
//   phase b: 16 MFMA (a1,bv) ; read bv(t+1),a0(t+1) from slot (t+1)&3
//   sched_barrier(0)   // pin slot-SC reads above end-bar (next body's stage-A overwrites SC)
//   end-bar
// Tail (slots 1,2,3 for both T=128 and T=12 since T%4==0): vmcnt 4 -> 0 -> none.

__device__ __forceinline__ void stage2(const bf16_t* __restrict__ G, int k0,
                                       bf16_t* lbase, size_t g0, size_t g1, int tid) {
  __builtin_amdgcn_global_load_lds(
      (const __attribute__((address_space(1))) void*)(G + g0 + k0),
      (__attribute__((address_space(3))) void*)(lbase + tid * 8), 16, 0, 0);
  __builtin_amdgcn_global_load_lds(
      (const __attribute__((address_space(1))) void*)(G + g1 + k0),
      (__attribute__((address_space(3))) void*)(lbase + 4096 + tid * 8), 16, 0, 0);
}

template <int N>
__device__ __forceinline__ void vm_wait() {
  if constexpr (N == 8)      asm volatile("s_waitcnt vmcnt(8)" ::: "memory");
  else if constexpr (N == 4) asm volatile("s_waitcnt vmcnt(4)" ::: "memory");
  else if constexpr (N == 0) asm volatile("s_waitcnt vmcnt(0)" ::: "memory");
}

// one 16-MFMA quadrant cluster, acc rows MB..MB+3
template <int MB>
__device__ __forceinline__ void mfma16(f32x4_t (&acc)[8][4], const bf16x8_t (&af)[4],
                                       const bf16x8_t (&bv)[4]) {
  __builtin_amdgcn_s_setprio(1);
  #pragma unroll
  for (int mi = 0; mi < 4; ++mi)
    #pragma unroll
    for (int nj = 0; nj < 4; ++nj)
      acc[MB + mi][nj] =
          __builtin_amdgcn_mfma_f32_16x16x32_bf16(af[mi], bv[nj], acc[MB + mi][nj], 0, 0, 0);
  __builtin_amdgcn_s_setprio(0);
}

// pipelined tile body. bv/a0 carried by reference across bodies.
template <int SC, bool STAGE, int VMN, bool NEXTRD>
__device__ __forceinline__ void tbodyP(f32x4_t (&acc)[8][4], bf16_t* sring,
                                       const bf16_t* __restrict__ Ag,
                                       const bf16_t* __restrict__ Bg, int k3,
                                       size_t gA0, size_t gA1, size_t gB0, size_t gB1,
                                       int aoff, int boff, int tid,
                                       bf16x8_t (&bv)[4], bf16x8_t (&a0)[4]) {
  constexpr int SS = (SC + 3) & 3;
  constexpr int SN = (SC + 1) & 3;
  if constexpr (STAGE) stage2(Ag, k3, sring + SS * 16384, gA0, gA1, tid);
  const bf16_t* pA = sring + SC * 16384 + aoff;
  bf16x8_t a1[4];
  mfma16<0>(acc, a0, bv);                       // operands pre-read last phase
  #pragma unroll
  for (int mi = 0; mi < 4; ++mi) a1[mi] = *(const bf16x8_t*)(pA + (4 + mi) * 512);
  if constexpr (STAGE) stage2(Bg, k3, sring + SS * 16384 + 8192, gB0, gB1, tid);
  vm_wait<VMN>();
  __builtin_amdgcn_s_barrier();                 // mid: tile t+1 visible from here
  mfma16<4>(acc, a1, bv);
  if constexpr (NEXTRD) {
    const bf16_t* qA = sring + SN * 16384 + aoff;
    const bf16_t* qB = sring + SN * 16384 + 8192 + boff;
    #pragma unroll
    for (int nj = 0; nj < 4; ++nj) bv[nj] = *(const bf16x8_t*)(qB + nj * 512);
    #pragma unroll
    for (int mi = 0; mi < 4; ++mi) a0[mi] = *(const bf16x8_t*)(qA + mi * 512);
  }
  __builtin_amdgcn_sched_barrier(0);            // pin slot-SC reads above end-bar
  __builtin_amdgcn_s_barrier();                 // end: slot SC re-stageable
}

template <int K>
__device__ __forceinline__ void kloopP(f32x4_t (&acc)[8][4], bf16_t* sring,
                                       const bf16_t* __restrict__ A, int lda,
                                       const bf16_t* __restrict__ B, int ldb,
                                       int tid, int aoff, int boff) {
  constexpr int T = K / 32;                 // 128 and 12; both T%4==0
  static_assert((T & 3) == 0, "T must be multiple of 4");
  // per-thread staging source offsets (16B slot s: row=s>>2, chunk'=s&3, src chunk
  // inverse-swizzled per rule 21) -- loop-invariant
  const int s0 = tid,       r0 = s0 >> 2, c0 = (s0 & 3) ^ ((r0 >> 1) & 3);
  const int s1 = 512 + tid, r1 = s1 >> 2, c1 = (s1 & 3) ^ ((r1 >> 1) & 3);
  const size_t gA0 = (size_t)r0 * lda + c0 * 8, gA1 = (size_t)r1 * lda + c1 * 8;
  const size_t gB0 = (size_t)r0 * ldb + c0 * 8, gB1 = (size_t)r1 * ldb + c1 * 8;

  #pragma unroll
  for (int t = 0; t < 3; ++t) {             // prologue: tiles 0..2 -> slots 0..2 (12 glds)
    stage2(A, t * 32, sring + t * 16384, gA0, gA1, tid);
    stage2(B, t * 32, sring + t * 16384 + 8192, gB0, gB1, tid);
  }
  asm volatile("s_waitcnt vmcnt(8)" ::: "memory");   // tile 0 landed (oldest 4 of 12)
  __builtin_amdgcn_s_barrier();
  bf16x8_t bv[4], a0[4];
  {
    const bf16_t* qA = sring + aoff;
    const bf16_t* qB = sring + 8192 + boff;
    #pragma unroll
    for (int nj = 0; nj < 4; ++nj) bv[nj] = *(const bf16x8_t*)(qB + nj * 512);
    #pragma unroll
    for (int mi = 0; mi < 4; ++mi) a0[mi] = *(const bf16x8_t*)(qA + mi * 512);
  }
  constexpr int TM = T - 3;                 // TM % 4 == 1 -> leftover is slot 0
  int t = 0;
  for (; t + 3 < TM; t += 4) {
    tbodyP<0,true,8,true>(acc, sring, A, B, (t+3)*32, gA0,gA1,gB0,gB1, aoff,boff,tid, bv,a0);
    tbodyP<1,true,8,true>(acc, sring, A, B, (t+4)*32, gA0,gA1,gB0,gB1, aoff,boff,tid, bv,a0);
    tbodyP<2,true,8,true>(acc, sring, A, B, (t+5)*32, gA0,gA1,gB0,gB1, aoff,boff,tid, bv,a0);
    tbodyP<3,true,8,true>(acc, sring, A, B, (t+6)*32, gA0,gA1,gB0,gB1, aoff,boff,tid, bv,a0);
  }
  // leftover: exactly one body, slot 0, stages tile T-1
  tbodyP<0,true,8,true>(acc, sring, A, B, (t+3)*32, gA0,gA1,gB0,gB1, aoff,boff,tid, bv,a0);
  // tail tiles T-3,T-2,T-1 (slots 1,2,3): no stages; drain 4 -> 0 -> none
  tbodyP<1,false,4,true >(acc, sring, A, B, 0, gA0,gA1,gB0,gB1, aoff,boff,tid, bv,a0);
  tbodyP<2,false,0,true >(acc, sring, A, B, 0, gA0,gA1,gB0,gB1, aoff,boff,tid, bv,a0);
  tbodyP<3,false,-1,false>(acc, sring, A, B, 0, gA0,gA1,gB0,gB1, aoff,boff,tid, bv,a0);
}

// 512 threads = 8 waves (2 M-groups x 4 N-groups); per-wave output 128x64.
// LDS: 4-slot ring x 16 KiB (A 8K | B 8K elems bf16) = 128 KiB -> 1 block/CU.
__global__ __launch_bounds__(512, 1) void gemm_fused256(const bf16_t* __restrict__ xb,
                                                        const bf16_t* __restrict__ WbT,
                                                        const bf16_t* __restrict__ C2b,
                                                        const bf16_t* __restrict__ BbT,
                                                        float* __restrict__ out) {
  __shared__ __align__(16) bf16_t sring[4 * 16384];  // [slot][A 8192 | B 8192]
  const int tid = threadIdx.x;
  const int lane = tid & 63;
  const int w = tid >> 6;
  const int wm = w >> 2;          // 0..1
  const int wn = w & 3;           // 0..3
  const int qd = lane >> 4;       // k-chunk
  const int ln = lane & 15;       // row-in-frag
  const int swz8 = ((qd ^ ((ln >> 1) & 3)) << 3);  // swizzled k-chunk, elem units

  // XCD-aware bijective swizzle (256 blocks, 256 % 8 == 0)
  int b = blockIdx.x;
  int sw = (b & 7) * 32 + (b >> 3);
  int bm = sw >> 4, bn = sw & 15;

  const int aoff = (wm * 128 + ln) * 32 + swz8;
  const int boff = (wn * 64 + ln) * 32 + swz8;

  f32x4_t acc[8][4] = {};

  kloopP<D_IN>(acc, sring, xb  + (size_t)bm * 256 * D_IN, D_IN,
                           WbT + (size_t)bn * 256 * D_IN, D_IN, tid, aoff, boff);
  kloopP<KC2>(acc, sring, C2b + (size_t)bm * 256 * KC2,  KC2,
                          BbT + (size_t)bn * 256 * KC2,  KC2,  tid, aoff, boff);

  float* Cb = out + (size_t)(bm * 256 + wm * 128) * O_OUT + bn * 256 + wn * 64;
  #pragma unroll
  for (int mi = 0; mi < 8; ++mi)
    #pragma unroll
    for (int nj = 0; nj < 4; ++nj)
      #pragma unroll
      for (int rg = 0; rg < 4; ++rg)
        Cb[(size_t)(mi * 16 + qd * 4 + rg) * O_OUT + nj * 16 + ln] = acc[mi][nj][rg];
}

// ---------------- launch ----------------
// ws layout (bytes):
//   xb    @ 0         : 33554432  (bf16 [4096,4096])
//   WbT   @ 33554432  : 33554432  (bf16 [4096,4096])
//   PabT  @ 67108864  : 2097152   (bf16 [256,4096])
//   BbT   @ 69206016  : 3145728   (bf16 [4096,384])
//   C2b   @ 72351744  : 3145728   (bf16 [4096,384])
//   gidx  @ 75497472  : 32768
//   gwv   @ 75530240  : 32768
// projP [8][4096][256] fp32 (32 MB) lives in d_out (dead until final GEMM overwrites).
extern "C" void kernel_launch(void* const* d_in, const int* in_sizes, int n_in,
                              void* d_out, int out_size, void* d_ws, size_t ws_size,
                              hipStream_t stream) {
  const float* x       = (const float*)d_in[0];
  const float* base_W  = (const float*)d_in[1];
  const float* routerW = (const float*)d_in[2];
  const float* A       = (const float*)d_in[3];
  const float* B       = (const float*)d_in[4];
  const float* Rm      = (const float*)d_in[5];
  float* out = (float*)d_out;
  char* ws = (char*)d_ws;

  bf16_t* xb   = (bf16_t*)(ws);
  bf16_t* WbT  = (bf16_t*)(ws + 33554432);
  bf16_t* PabT = (bf16_t*)(ws + 67108864);
  bf16_t* BbT  = (bf16_t*)(ws + 69206016);
  bf16_t* C2b  = (bf16_t*)(ws + 72351744);
  int*    gidx = (int*)   (ws + 75497472);
  float*  gwv  = (float*) (ws + 75530240);
  float*  projP = out;  // scratch: fully dead before gemm_fused writes out

  // 1) all independent prep in one saturating launch
  prep_kernel<<<5760, 256, 0, stream>>>(x, base_W, routerW, A, B, Rm,
                                        xb, WbT, BbT, PabT, gidx, gwv);
  // 2) proj split-K GEMM (non-atomic partials into d_out scratch), 2 blocks/CU
  gemm_proj_kernel<<<dim3(32, 2, NKZ), 256, 0, stream>>>(xb, PabT, projP);
  // 3) gating -> C2 (sums NKZ partials)
  gating_kernel<<<4096, 384, 0, stream>>>(projP, gidx, gwv, C2b);
  // 4) fused base+delta GEMM, phase-pipelined ring-4 counted-vmcnt, single out write
  gemm_fused256<<<dim3(256), 512, 0, stream>>>(xb, WbT, C2b, BbT, out);
}